// Round 7
// baseline (401.014 us; speedup 1.0000x reference)
//
#include <hip/hip_runtime.h>

#define NU 50000
#define NI 50000
#define NN 100000
#define NE 1600000
#define NP 200000
#define DIM 128
#define HID 64

// hist: 2 node ranges (100KB LDS each) x 64 edge chunks, one edge-array per kernel.
#define HR2 2
#define HC2 64
#define RN2 (NN / HR2)    // 50000 nodes per range
#define RNW2 (RN2 / 2)    // 25000 packed u16-pair words (100KB)
#define CE2 (NE / HC2)    // 25000 edges per chunk

// fill: 4 node ranges (100KB i32 cursor) x 64 chunks -> 256 blocks (full grid).
#define HRF 4
#define RNF (NN / HRF)    // 25000 nodes per range

typedef unsigned short bf16_t;
typedef __attribute__((ext_vector_type(8))) short short8;
typedef __attribute__((ext_vector_type(4))) float f32x4;
typedef __attribute__((ext_vector_type(2))) float f32x2;

__device__ __forceinline__ float bf2f(unsigned short u) {
  union { unsigned int i; float f; } c; c.i = ((unsigned int)u) << 16; return c.f;
}
__device__ __forceinline__ unsigned short f2bf(float f) {
  union { float f; unsigned int i; } c; c.f = f;
  unsigned int i = c.i;
  i += 0x7fffu + ((i >> 16) & 1u);   // RNE
  return (unsigned short)(i >> 16);
}
// packed bf16 pair -> f32x2 {lo, hi}; enables v_pk_add_f32 accumulate
__device__ __forceinline__ f32x2 unpack2(unsigned int w) {
  union { unsigned int i; float f; } lo, hi;
  lo.i = w << 16;
  hi.i = w & 0xffff0000u;
  f32x2 r; r.x = lo.f; r.y = hi.f;
  return r;
}
__device__ __forceinline__ int geti(const void* p, int i, bool i64) {
  return i64 ? (int)((const long long*)p)[i] : ((const int*)p)[i];
}

// ---------------- dtype probes ----------------
__global__ __launch_bounds__(64) void k_detect(const bf16_t* __restrict__ uf,
                                               const int* __restrict__ ei,
                                               int* __restrict__ flag) {
  int lane = threadIdx.x;
  float m = 0.f;
  for (int i = lane; i < 4096; i += 64) {
    float v = fabsf(bf2f(uf[i]));
    if (v < 3e38f) m = fmaxf(m, v);
  }
  int cnt = 0;
  for (int i = lane; i < 4096; i += 64) {
    if (ei[2 * i + 1] == 0) cnt++;
  }
  for (int off = 32; off > 0; off >>= 1) {
    m = fmaxf(m, __shfl_xor(m, off));
    cnt += __shfl_xor(cnt, off);
  }
  if (lane == 0) {
    flag[0] = (m > 100.f) ? 1 : 0;   // fp32 floats
    flag[1] = (cnt > 2048) ? 1 : 0;  // int64 ints
  }
}

// ---------------- single-array LDS histogram: per-(range,chunk) u16 counts ----------------
__global__ __launch_bounds__(1024) void k_hist1(const void* __restrict__ ev,
                                                const int* __restrict__ flag,
                                                unsigned int* __restrict__ part) {
  __shared__ unsigned int h[RNW2];   // 100 KB
  const bool i64 = (flag[1] != 0);
  int r = blockIdx.x & (HR2 - 1);
  int c = blockIdx.x >> 1;
  int lo = r * RN2, hiN = lo + RN2;
  int t = threadIdx.x;
  for (int i = t; i < RNW2; i += 1024) h[i] = 0u;
  __syncthreads();
  int ebeg = c * CE2;
  if (!i64) {
    const int* p = (const int*)ev + ebeg;
    for (int e = t * 4; e < CE2; e += 1024 * 4) {
      int4 v4 = *(const int4*)(p + e);
      int vv[4] = {v4.x, v4.y, v4.z, v4.w};
#pragma unroll
      for (int k = 0; k < 4; ++k) {
        int v = vv[k];
        if (v >= lo && v < hiN) {
          int loc = v - lo;
          atomicAdd(&h[loc >> 1], 1u << ((loc & 1) * 16));
        }
      }
    }
  } else {
    const long long* p = (const long long*)ev + ebeg;
    for (int e = t; e < CE2; e += 1024) {
      int v = (int)p[e];
      if (v >= lo && v < hiN) {
        int loc = v - lo;
        atomicAdd(&h[loc >> 1], 1u << ((loc & 1) * 16));
      }
    }
  }
  __syncthreads();
  unsigned int* po = part + c * (NN / 2) + (lo >> 1);
  for (int i = t; i < RNW2; i += 1024) po[i] = h[i];
}

// ---------------- reduce packed partials: totals + norms + u16 prefix + block sums ----------------
__global__ __launch_bounds__(256) void k_reduce(const unsigned int* __restrict__ pout,
                                                unsigned int* __restrict__ pin,
                                                int* __restrict__ din,
                                                float* __restrict__ onorm,
                                                float* __restrict__ inorm,
                                                int* __restrict__ bsums) {
  __shared__ int sh[256];
  int t = threadIdx.x;
  int w = blockIdx.x * 256 + t;
  unsigned int si0 = 0, si1 = 0;
  if (w < NN / 2) {
    unsigned int so0 = 0, so1 = 0;
#pragma unroll
    for (int c = 0; c < HC2; ++c) {
      unsigned int v = pout[c * (NN / 2) + w];
      so0 += v & 0xffffu;
      so1 += v >> 16;
    }
#pragma unroll
    for (int c = 0; c < HC2; ++c) {
      unsigned int v = pin[c * (NN / 2) + w];
      pin[c * (NN / 2) + w] = si0 | (si1 << 16);   // exclusive per-chunk offsets
      si0 += v & 0xffffu;
      si1 += v >> 16;
    }
    int n = 2 * w;
    din[n] = (int)si0;
    din[n + 1] = (int)si1;
    onorm[n] = rsqrtf((float)(so0 > 1u ? so0 : 1u));
    onorm[n + 1] = rsqrtf((float)(so1 > 1u ? so1 : 1u));
    inorm[n] = rsqrtf((float)(si0 > 1u ? si0 : 1u));
    inorm[n + 1] = rsqrtf((float)(si1 > 1u ? si1 : 1u));
  }
  sh[t] = (int)(si0 + si1);
  __syncthreads();
  for (int off = 128; off > 0; off >>= 1) {
    if (t < off) sh[t] += sh[t + off];
    __syncthreads();
  }
  if (t == 0) bsums[blockIdx.x] = sh[0];
}

__global__ __launch_bounds__(256) void k_scan2(const int* __restrict__ bsums,
                                               int* __restrict__ boffs, int nb) {
  __shared__ int sh[256];
  int t = threadIdx.x;
  int own = (t < nb) ? bsums[t] : 0;
  sh[t] = own;
  __syncthreads();
  for (int off = 1; off < 256; off <<= 1) {
    int add = (t >= off) ? sh[t - off] : 0;
    __syncthreads();
    sh[t] += add;
    __syncthreads();
  }
  if (t < nb) boffs[t] = sh[t] - own;
}

// 512 nodes per block (matches k_reduce block sums).
__global__ __launch_bounds__(256) void k_scan3(const int* __restrict__ in,
                                               const int* __restrict__ boffs,
                                               int* __restrict__ row_ptr,
                                               int* __restrict__ csr_src, int n) {
  __shared__ int sh[256];
  int t = threadIdx.x;
  int base = blockIdx.x * 512 + t * 2;
  int v0 = (base < n) ? in[base] : 0;
  int v1 = (base + 1 < n) ? in[base + 1] : 0;
  int s = v0 + v1;
  sh[t] = s;
  __syncthreads();
  for (int off = 1; off < 256; off <<= 1) {
    int add = (t >= off) ? sh[t - off] : 0;
    __syncthreads();
    sh[t] += add;
    __syncthreads();
  }
  int excl = boffs[blockIdx.x] + sh[t] - s;
  if (base < n) row_ptr[base] = excl;
  if (base + 1 < n) row_ptr[base + 1] = excl + v0;
  if (blockIdx.x == 0 && t == 0) row_ptr[n] = NE;
  // pad csr_src tail with zero-row index: gathers load csr_src[ee] unconditionally
  if (blockIdx.x == 0 && t < 32) csr_src[NE + t] = NN;
}

// ---------------- CSR fill via LDS cursors (zero global atomics), full grid ----------------
__global__ __launch_bounds__(1024) void k_fill2(const void* __restrict__ srcv,
                                                const void* __restrict__ dstv,
                                                const int* __restrict__ flag,
                                                const int* __restrict__ row_ptr,
                                                const unsigned int* __restrict__ pin,
                                                int* __restrict__ csr_src) {
  __shared__ int cur[RNF];   // 100 KB
  const bool i64 = (flag[1] != 0);
  int r = blockIdx.x & (HRF - 1);
  int c = blockIdx.x >> 2;
  int lo = r * RNF, hiN = lo + RNF;
  int t = threadIdx.x;
  const unsigned int* pw = pin + c * (NN / 2);
  const int* rp = row_ptr + lo;
  for (int i = t; i < RNF; i += 1024) {
    int node = lo + i;
    unsigned int wrd = pw[node >> 1];
    int off = (int)((wrd >> ((node & 1) * 16)) & 0xffffu);
    cur[i] = rp[i] + off;
  }
  __syncthreads();
  int ebeg = c * CE2;
  if (!i64) {
    const int* sp = (const int*)srcv + ebeg;
    const int* dp = (const int*)dstv + ebeg;
    for (int e = t * 4; e < CE2; e += 1024 * 4) {
      int4 dv = *(const int4*)(dp + e);
      int4 sv = *(const int4*)(sp + e);
      int dd[4] = {dv.x, dv.y, dv.z, dv.w};
      int ss[4] = {sv.x, sv.y, sv.z, sv.w};
#pragma unroll
      for (int k = 0; k < 4; ++k) {
        int d = dd[k];
        if (d >= lo && d < hiN) {
          int slot = atomicAdd(&cur[d - lo], 1);
          csr_src[slot] = ss[k];
        }
      }
    }
  } else {
    const long long* sp = (const long long*)srcv + ebeg;
    const long long* dp = (const long long*)dstv + ebeg;
    for (int e = t; e < CE2; e += 1024) {
      int d = (int)dp[e];
      if (d >= lo && d < hiN) {
        int slot = atomicAdd(&cur[d - lo], 1);
        csr_src[slot] = (int)sp[e];
      }
    }
  }
}

// ---------------- embed: relu(X@W+b) -> fp32 out + bf16 out-norm-scaled copy ----------------
__global__ __launch_bounds__(256) void k_embed(const void* __restrict__ featv,
                                               const void* __restrict__ Wv,
                                               const void* __restrict__ biasv,
                                               const int* __restrict__ flag,
                                               const float* __restrict__ onorm_base,
                                               float* __restrict__ out,
                                               bf16_t* __restrict__ embs,
                                               bf16_t* __restrict__ zrow, int rows) {
  __shared__ float Ws[DIM * HID];  // 32 KB
  __shared__ float bs[HID];
  const bool f32 = (flag[0] != 0);
  int t = threadIdx.x;
  if (zrow && blockIdx.x == 0 && t < 32)
    ((unsigned int*)zrow)[t] = 0u;   // zeros row at table index NN
  if (f32) {
    const float* W = (const float*)Wv;
    for (int i = t; i < DIM * HID; i += 256) Ws[i] = W[i];
    if (t < HID) bs[t] = ((const float*)biasv)[t];
  } else {
    const bf16_t* W = (const bf16_t*)Wv;
    for (int i = t; i < DIM * HID; i += 256) Ws[i] = bf2f(W[i]);
    if (t < HID) bs[t] = bf2f(((const bf16_t*)biasv)[t]);
  }
  __syncthreads();
  int rl = t >> 4;
  int jq = t & 15;
  for (int rbase = blockIdx.x * 16; rbase < rows; rbase += gridDim.x * 16) {
    int row = rbase + rl;
    if (row >= rows) continue;
    float a0 = 0.f, a1 = 0.f, a2 = 0.f, a3 = 0.f;
    if (f32) {
      const float* fr = (const float*)featv + (size_t)row * DIM;
      for (int k0 = 0; k0 < DIM; k0 += 4) {
        float4 f4 = *(const float4*)(fr + k0);
        float fk[4] = {f4.x, f4.y, f4.z, f4.w};
#pragma unroll
        for (int kk = 0; kk < 4; ++kk) {
          const float* wr = &Ws[(k0 + kk) * HID + jq * 4];
          a0 += fk[kk] * wr[0];
          a1 += fk[kk] * wr[1];
          a2 += fk[kk] * wr[2];
          a3 += fk[kk] * wr[3];
        }
      }
    } else {
      const bf16_t* fr = (const bf16_t*)featv + (size_t)row * DIM;
      for (int k0 = 0; k0 < DIM; k0 += 8) {
        uint4 u = *(const uint4*)(fr + k0);
        unsigned int w[4] = {u.x, u.y, u.z, u.w};
#pragma unroll
        for (int kk = 0; kk < 8; ++kk) {
          unsigned short us = (unsigned short)((w[kk >> 1] >> ((kk & 1) * 16)) & 0xffffu);
          float fk = bf2f(us);
          const float* wr = &Ws[(k0 + kk) * HID + jq * 4];
          a0 += fk * wr[0];
          a1 += fk * wr[1];
          a2 += fk * wr[2];
          a3 += fk * wr[3];
        }
      }
    }
    float4 r;
    r.x = fmaxf(a0 + bs[jq * 4 + 0], 0.f);
    r.y = fmaxf(a1 + bs[jq * 4 + 1], 0.f);
    r.z = fmaxf(a2 + bs[jq * 4 + 2], 0.f);
    r.w = fmaxf(a3 + bs[jq * 4 + 3], 0.f);
    *(float4*)&out[(size_t)row * HID + jq * 4] = r;
    float sc = onorm_base[row];
    uint2 p;
    p.x = (unsigned int)f2bf(r.x * sc) | ((unsigned int)f2bf(r.y * sc) << 16);
    p.y = (unsigned int)f2bf(r.z * sc) | ((unsigned int)f2bf(r.w * sc) << 16);
    *(uint2*)&embs[(size_t)row * HID + jq * 4] = p;
  }
}

// ---------------- gather layer 1: TWO nodes per wave ----------------
__global__ __launch_bounds__(256) void k_gather1(const bf16_t* __restrict__ embs,
                                                 const float* __restrict__ onorm,
                                                 const float* __restrict__ inorm,
                                                 const int* __restrict__ row_ptr,
                                                 const int* __restrict__ csr_src,
                                                 bf16_t* __restrict__ e1s) {
  if (blockIdx.x == 0 && threadIdx.x < 32)
    ((unsigned int*)(e1s + (size_t)NN * HID))[threadIdx.x] = 0u;  // e1s zeros row
  int lane = threadIdx.x & 63;
  int h = lane >> 5;            // node sub-id within wave
  int g = (lane >> 3) & 3;      // 4 edge-groups
  int l8 = (lane & 7) * 8;      // column base (8 bf16 = 16B per lane)
  int n = blockIdx.x * 8 + (threadIdx.x >> 6) * 2 + h;
  int beg = row_ptr[n], end = row_ptr[n + 1];
  f32x2 a[4];
#pragma unroll
  for (int j = 0; j < 4; ++j) a[j] = (f32x2)(0.f);
  for (int base = beg; base < end; base += 16) {
    int sv[4];
#pragma unroll
    for (int k = 0; k < 4; ++k) {
      int ee = base + k * 4 + g;
      int raw = csr_src[ee];          // always in-bounds (32-entry pad)
      sv[k] = (ee < end) ? raw : NN;  // tail -> zeros row
    }
#pragma unroll
    for (int k = 0; k < 4; ++k) {
      uint4 u = *(const uint4*)(embs + (sv[k] << 6) + l8);
      a[0] += unpack2(u.x);
      a[1] += unpack2(u.y);
      a[2] += unpack2(u.z);
      a[3] += unpack2(u.w);
    }
  }
#pragma unroll
  for (int j = 0; j < 4; ++j) {    // reduce over g (stays within half-wave)
    a[j].x += __shfl_xor(a[j].x, 8);
    a[j].y += __shfl_xor(a[j].y, 8);
    a[j].x += __shfl_xor(a[j].x, 16);
    a[j].y += __shfl_xor(a[j].y, 16);
  }
  if (g == 0) {
    float sc = inorm[n] * onorm[n];   // pre-scale for next gather
    uint4 p;
    p.x = (unsigned int)f2bf(a[0].x * sc) | ((unsigned int)f2bf(a[0].y * sc) << 16);
    p.y = (unsigned int)f2bf(a[1].x * sc) | ((unsigned int)f2bf(a[1].y * sc) << 16);
    p.z = (unsigned int)f2bf(a[2].x * sc) | ((unsigned int)f2bf(a[2].y * sc) << 16);
    p.w = (unsigned int)f2bf(a[3].x * sc) | ((unsigned int)f2bf(a[3].y * sc) << 16);
    *(uint4*)(e1s + (size_t)n * HID + l8) = p;
  }
}

// ---------------- gather layer 2 + combine + side; TWO nodes per wave ----------------
__global__ __launch_bounds__(256) void k_gather2c(float* __restrict__ emb0,
                                                  const bf16_t* __restrict__ e1s,
                                                  const void* __restrict__ sidev,
                                                  const int* __restrict__ flag,
                                                  const float* __restrict__ onorm,
                                                  const float* __restrict__ inorm,
                                                  const int* __restrict__ row_ptr,
                                                  const int* __restrict__ csr_src,
                                                  bf16_t* __restrict__ fin_bf) {
  int lane = threadIdx.x & 63;
  int h = lane >> 5;
  int g = (lane >> 3) & 3;
  int l8 = (lane & 7) * 8;
  int n = blockIdx.x * 8 + (threadIdx.x >> 6) * 2 + h;
  int beg = row_ptr[n], end = row_ptr[n + 1];
  f32x2 a[4];
#pragma unroll
  for (int j = 0; j < 4; ++j) a[j] = (f32x2)(0.f);
  for (int base = beg; base < end; base += 16) {
    int sv[4];
#pragma unroll
    for (int k = 0; k < 4; ++k) {
      int ee = base + k * 4 + g;
      int raw = csr_src[ee];
      sv[k] = (ee < end) ? raw : NN;
    }
#pragma unroll
    for (int k = 0; k < 4; ++k) {
      uint4 u = *(const uint4*)(e1s + (sv[k] << 6) + l8);
      a[0] += unpack2(u.x);
      a[1] += unpack2(u.y);
      a[2] += unpack2(u.z);
      a[3] += unpack2(u.w);
    }
  }
#pragma unroll
  for (int j = 0; j < 4; ++j) {
    a[j].x += __shfl_xor(a[j].x, 8);
    a[j].y += __shfl_xor(a[j].y, 8);
    a[j].x += __shfl_xor(a[j].x, 16);
    a[j].y += __shfl_xor(a[j].y, 16);
  }
  if (g == 0) {
    float aa[8] = {a[0].x, a[0].y, a[1].x, a[1].y, a[2].x, a[2].y, a[3].x, a[3].y};
    float inorm_n = inorm[n];
    float inv_on = 1.0f / onorm[n];     // e1 = e1s / onorm
    size_t off = (size_t)n * HID + l8;
    uint4 u = *(const uint4*)(e1s + off);
    unsigned int w[4] = {u.x, u.y, u.z, u.w};
    float e1v[8];
#pragma unroll
    for (int j = 0; j < 4; ++j) {
      e1v[2 * j]     = bf2f((unsigned short)(w[j] & 0xffffu)) * inv_on;
      e1v[2 * j + 1] = bf2f((unsigned short)(w[j] >> 16)) * inv_on;
    }
    float4 b0 = *(const float4*)&emb0[off];
    float4 b1 = *(const float4*)&emb0[off + 4];
    float bb[8] = {b0.x, b0.y, b0.z, b0.w, b1.x, b1.y, b1.z, b1.w};
    const float s2 = 1.f / 3.f;
    float vv[8];
#pragma unroll
    for (int j = 0; j < 8; ++j)
      vv[j] = bb[j] + 0.5f * e1v[j] + s2 * aa[j] * inorm_n;
    if (n >= NU) {
      size_t soff = (size_t)(n - NU) * HID + l8;
      if (flag[0] != 0) {
        float4 s0 = *(const float4*)((const float*)sidev + soff);
        float4 s1 = *(const float4*)((const float*)sidev + soff + 4);
        vv[0] += s0.x; vv[1] += s0.y; vv[2] += s0.z; vv[3] += s0.w;
        vv[4] += s1.x; vv[5] += s1.y; vv[6] += s1.z; vv[7] += s1.w;
      } else {
        uint4 su = *(const uint4*)((const bf16_t*)sidev + soff);
        unsigned int sw[4] = {su.x, su.y, su.z, su.w};
#pragma unroll
        for (int j = 0; j < 4; ++j) {
          vv[2 * j]     += bf2f((unsigned short)(sw[j] & 0xffffu));
          vv[2 * j + 1] += bf2f((unsigned short)(sw[j] >> 16));
        }
      }
    }
    float4 o0, o1;
    o0.x = vv[0]; o0.y = vv[1]; o0.z = vv[2]; o0.w = vv[3];
    o1.x = vv[4]; o1.y = vv[5]; o1.z = vv[6]; o1.w = vv[7];
    *(float4*)&emb0[off] = o0;
    *(float4*)&emb0[off + 4] = o1;
    uint4 pb;
    pb.x = (unsigned int)f2bf(vv[0]) | ((unsigned int)f2bf(vv[1]) << 16);
    pb.y = (unsigned int)f2bf(vv[2]) | ((unsigned int)f2bf(vv[3]) << 16);
    pb.z = (unsigned int)f2bf(vv[4]) | ((unsigned int)f2bf(vv[5]) << 16);
    pb.w = (unsigned int)f2bf(vv[6]) | ((unsigned int)f2bf(vv[7]) << 16);
    *(uint4*)(fin_bf + off) = pb;
  }
}

// ---------------- decode via MFMA, pos/neg fused, 2-deep software pipeline ----------------
// Next tile's ids are loaded before the current MFMA block; next tile's A-fragments
// are issued right after the MFMAs so their latency hides under the epilogue VALU.
// Epilogue consumes acc[nt] immediately after its MFMAs (same nt order -> bit-identical).
__global__ __launch_bounds__(256) void k_decode(const bf16_t* __restrict__ zb,  // fin_bf
                                                const void* __restrict__ W1v,
                                                const void* __restrict__ b1v,
                                                const void* __restrict__ W2v,
                                                const void* __restrict__ Tfv,
                                                const void* __restrict__ Tcfv,
                                                const int* __restrict__ flag,
                                                const void* __restrict__ userId,
                                                const void* __restrict__ posId,
                                                const void* __restrict__ negId,
                                                float* __restrict__ out_lf,
                                                float* __restrict__ out_lcf) {
  __shared__ bf16_t W1b[128 * 65];   // padded rows (65) to dodge LDS bank conflicts
  __shared__ float wlast[HID], b1s[HID], W2s[HID];
  const bool f32 = (flag[0] != 0);
  const bool i64 = (flag[1] != 0);
  int t = threadIdx.x;
  if (f32) {
    const float* W1 = (const float*)W1v;
    for (int i = t; i < 128 * 64; i += 256) W1b[(i >> 6) * 65 + (i & 63)] = f2bf(W1[i]);
    if (t < HID) {
      wlast[t] = W1[128 * 64 + t];
      b1s[t] = ((const float*)b1v)[t];
      W2s[t] = ((const float*)W2v)[t];
    }
  } else {
    const bf16_t* W1 = (const bf16_t*)W1v;
    for (int i = t; i < 128 * 64; i += 256) W1b[(i >> 6) * 65 + (i & 63)] = W1[i];
    if (t < HID) {
      wlast[t] = bf2f(W1[128 * 64 + t]);
      b1s[t] = bf2f(((const bf16_t*)b1v)[t]);
      W2s[t] = bf2f(((const bf16_t*)W2v)[t]);
    }
  }
  __syncthreads();
  int wv = t >> 6;
  int lane = t & 63;
  int m = lane & 15;     // A row within tile / B col
  int q = lane >> 4;     // k-subchunk
  short8 Bf[4][4];
#pragma unroll
  for (int c = 0; c < 4; ++c)
#pragma unroll
    for (int nt = 0; nt < 4; ++nt)
#pragma unroll
      for (int j = 0; j < 8; ++j)
        Bf[c][nt][j] = (short)W1b[(c * 32 + q * 8 + j) * 65 + nt * 16 + m];

  const int tiles = NP / 16;  // 12500 pair-tiles
  const int stride = gridDim.x * 4;
  int tile = blockIdx.x * 4 + wv;
  if (tile >= tiles) return;

  // prologue: load first tile's ids + fragments
  int pid = tile * 16 + m;
  int uid = geti(userId, pid, i64);
  int pidx = geti(posId, pid, i64);
  int nidx = geti(negId, pid, i64);
  const bf16_t* ur = zb + (size_t)uid * HID;
  const bf16_t* pr = zb + (size_t)(NU + pidx) * HID;
  const bf16_t* nr = zb + (size_t)(NU + nidx) * HID;
  short8 au0 = *(const short8*)(ur + q * 8);
  short8 au1 = *(const short8*)(ur + 32 + q * 8);
  short8 ap0 = *(const short8*)(pr + q * 8);
  short8 ap1 = *(const short8*)(pr + 32 + q * 8);
  short8 an0 = *(const short8*)(nr + q * 8);
  short8 an1 = *(const short8*)(nr + 32 + q * 8);

  while (true) {
    int ntile = tile + stride;
    bool have_next = (ntile < tiles);
    int uid2 = 0, pidx2 = 0, nidx2 = 0;
    if (have_next) {               // issue next ids early (hide under MFMA)
      int pid2 = ntile * 16 + m;
      uid2 = geti(userId, pid2, i64);
      pidx2 = geti(posId, pid2, i64);
      nidx2 = geti(negId, pid2, i64);
    }
    // T values for current tile
    float tf_p[4], tc_p[4], tf_n[4], tc_n[4];
    int rbase = tile * 16 + q * 4;
    if (f32) {
      float4 t4 = *(const float4*)((const float*)Tfv + rbase);
      float4 c4 = *(const float4*)((const float*)Tcfv + rbase);
      float4 t4n = *(const float4*)((const float*)Tfv + rbase + NP);
      float4 c4n = *(const float4*)((const float*)Tcfv + rbase + NP);
      tf_p[0] = t4.x; tf_p[1] = t4.y; tf_p[2] = t4.z; tf_p[3] = t4.w;
      tc_p[0] = c4.x; tc_p[1] = c4.y; tc_p[2] = c4.z; tc_p[3] = c4.w;
      tf_n[0] = t4n.x; tf_n[1] = t4n.y; tf_n[2] = t4n.z; tf_n[3] = t4n.w;
      tc_n[0] = c4n.x; tc_n[1] = c4n.y; tc_n[2] = c4n.z; tc_n[3] = c4n.w;
    } else {
      const bf16_t* tp = (const bf16_t*)Tfv + rbase;
      const bf16_t* cp = (const bf16_t*)Tcfv + rbase;
#pragma unroll
      for (int r = 0; r < 4; ++r) {
        tf_p[r] = bf2f(tp[r]); tc_p[r] = bf2f(cp[r]);
        tf_n[r] = bf2f(tp[r + NP]); tc_n[r] = bf2f(cp[r + NP]);
      }
    }
    // MFMA + streaming epilogue accumulation (per-nt, same order as before)
    float sfp[4], scp[4], sfn[4], scn[4];
#pragma unroll
    for (int r = 0; r < 4; ++r) { sfp[r] = 0.f; scp[r] = 0.f; sfn[r] = 0.f; scn[r] = 0.f; }
#pragma unroll
    for (int nt = 0; nt < 4; ++nt) {
      f32x4 accu = (f32x4)(0.f);
      accu = __builtin_amdgcn_mfma_f32_16x16x32_bf16(au0, Bf[0][nt], accu, 0, 0, 0);
      accu = __builtin_amdgcn_mfma_f32_16x16x32_bf16(au1, Bf[1][nt], accu, 0, 0, 0);
      f32x4 accp = __builtin_amdgcn_mfma_f32_16x16x32_bf16(ap0, Bf[2][nt], accu, 0, 0, 0);
      accp = __builtin_amdgcn_mfma_f32_16x16x32_bf16(ap1, Bf[3][nt], accp, 0, 0, 0);
      f32x4 accn = __builtin_amdgcn_mfma_f32_16x16x32_bf16(an0, Bf[2][nt], accu, 0, 0, 0);
      accn = __builtin_amdgcn_mfma_f32_16x16x32_bf16(an1, Bf[3][nt], accn, 0, 0, 0);
      int n = nt * 16 + m;
      float b = b1s[n];
      float wl = wlast[n];
      float w2 = W2s[n];
#pragma unroll
      for (int r = 0; r < 4; ++r) {
        float xp = accp[r] + b;
        float xn = accn[r] + b;
        float v0 = xp + tf_p[r] * wl;
        float v1 = xp + tc_p[r] * wl;
        float v2 = xn + tf_n[r] * wl;
        float v3 = xn + tc_n[r] * wl;
        sfp[r] += (v0 > 0.f ? v0 : (__expf(v0) - 1.f)) * w2;
        scp[r] += (v1 > 0.f ? v1 : (__expf(v1) - 1.f)) * w2;
        sfn[r] += (v2 > 0.f ? v2 : (__expf(v2) - 1.f)) * w2;
        scn[r] += (v3 > 0.f ? v3 : (__expf(v3) - 1.f)) * w2;
      }
    }
    // issue next tile's fragment loads now; latency hides under shuffle reduce below
    short8 bu0 = au0, bu1 = au1, bp0 = ap0, bp1 = ap1, bn0 = an0, bn1 = an1;
    if (have_next) {
      const bf16_t* ur2 = zb + (size_t)uid2 * HID;
      const bf16_t* pr2 = zb + (size_t)(NU + pidx2) * HID;
      const bf16_t* nr2 = zb + (size_t)(NU + nidx2) * HID;
      bu0 = *(const short8*)(ur2 + q * 8);
      bu1 = *(const short8*)(ur2 + 32 + q * 8);
      bp0 = *(const short8*)(pr2 + q * 8);
      bp1 = *(const short8*)(pr2 + 32 + q * 8);
      bn0 = *(const short8*)(nr2 + q * 8);
      bn1 = *(const short8*)(nr2 + 32 + q * 8);
    }
#pragma unroll
    for (int r = 0; r < 4; ++r) {
#pragma unroll
      for (int s = 1; s < 16; s <<= 1) {
        sfp[r] += __shfl_xor(sfp[r], s);
        scp[r] += __shfl_xor(scp[r], s);
        sfn[r] += __shfl_xor(sfn[r], s);
        scn[r] += __shfl_xor(scn[r], s);
      }
      if (m == 0) {
        int pr2i = rbase + r;
        out_lf[pr2i] = sfp[r];
        out_lcf[pr2i] = scp[r];
        out_lf[pr2i + NP] = sfn[r];
        out_lcf[pr2i + NP] = scn[r];
      }
    }
    if (!have_next) break;
    tile = ntile;
    au0 = bu0; au1 = bu1; ap0 = bp0; ap1 = bp1; an0 = bn0; an1 = bn1;
  }
}

extern "C" void kernel_launch(void* const* d_in, const int* in_sizes, int n_in,
                              void* d_out, int out_size, void* d_ws, size_t ws_size,
                              hipStream_t stream) {
  (void)in_sizes; (void)n_in; (void)out_size;
  const void* user_f = d_in[0];
  const void* item_f = d_in[1];
  const void* side   = d_in[2];
  const void* Tf     = d_in[3];
  const void* Tcf    = d_in[4];
  const void* Wu     = d_in[5];
  const void* bu     = d_in[6];
  const void* Wi     = d_in[7];
  const void* bi     = d_in[8];
  const void* W1     = d_in[9];
  const void* b1     = d_in[10];
  const void* W2     = d_in[11];
  const void* esrc   = d_in[12];
  const void* edst   = d_in[13];
  const void* userId = d_in[14];
  const void* posId  = d_in[15];
  const void* negId  = d_in[16];

  const size_t WS_NEEDED = 33602688;
  if (ws_size < WS_NEEDED) return;

  char* ws = (char*)d_ws;
  int*   deg_in  = (int*)(ws + 0);             // 400000
  float* onorm   = (float*)(ws + 400000);      // 400000
  float* inorm   = (float*)(ws + 800000);      // 400000
  int*   row_ptr = (int*)(ws + 1200000);       // 400128 (NN+1 ints, padded)
  int*   bsums   = (int*)(ws + 1600128);       // 1024 (196 ints)
  int*   boffs   = (int*)(ws + 1601152);       // 1024
  int*   flag    = (int*)(ws + 1602176);       // 128
  int*   csr_src = (int*)(ws + 1602304);       // 6.4 MB + 128B pad (NE+32 ints)
  // partial histograms overlay embs/e1s (dead before embed/gather writes):
  unsigned int* pout = (unsigned int*)(ws + 8002432);   // 12.8 MB: [HC2][NN/2] u16-packed
  unsigned int* pin  = (unsigned int*)(ws + 20802560);  // 12.8 MB: ditto -> prefixes
  bf16_t* embs   = (bf16_t*)(ws + 8002432);    // (NN+1) rows bf16; later reused as fin_bf
  bf16_t* e1s    = (bf16_t*)(ws + 20802560);   // (NN+1) rows bf16
  bf16_t* fin_bf = embs;                       // embs dead after k_gather1 (stream-ordered)

  float* out     = (float*)d_out;
  float* emb0    = out;
  float* out_lf  = out + (size_t)NN * HID;
  float* out_lcf = out_lf + 2 * NP;

  k_detect<<<1, 64, 0, stream>>>((const bf16_t*)user_f, (const int*)esrc, flag);
  k_hist1<<<HR2 * HC2, 1024, 0, stream>>>(esrc, flag, pout);
  k_hist1<<<HR2 * HC2, 1024, 0, stream>>>(edst, flag, pin);
  k_reduce<<<196, 256, 0, stream>>>(pout, pin, deg_in, onorm, inorm, bsums);
  k_scan2<<<1, 256, 0, stream>>>(bsums, boffs, 196);
  k_scan3<<<196, 256, 0, stream>>>(deg_in, boffs, row_ptr, csr_src, NN);
  k_fill2<<<HRF * HC2, 1024, 0, stream>>>(esrc, edst, flag, row_ptr, pin, csr_src);
  k_embed<<<256, 256, 0, stream>>>(user_f, Wu, bu, flag, onorm, emb0, embs,
                                   embs + (size_t)NN * HID, NU);
  k_embed<<<256, 256, 0, stream>>>(item_f, Wi, bi, flag, onorm + NU,
                                   emb0 + (size_t)NU * HID, embs + (size_t)NU * HID,
                                   (bf16_t*)0, NI);
  k_gather1<<<NN / 8, 256, 0, stream>>>(embs, onorm, inorm, row_ptr, csr_src, e1s);
  k_gather2c<<<NN / 8, 256, 0, stream>>>(emb0, e1s, side, flag, onorm, inorm, row_ptr,
                                         csr_src, fin_bf);
  k_decode<<<1024, 256, 0, stream>>>(fin_bf, W1, b1, W2, Tf, Tcf, flag,
                                     userId, posId, negId, out_lf, out_lcf);
}

// Round 8
// 386.818 us; speedup vs baseline: 1.0367x; 1.0367x over previous
//
#include <hip/hip_runtime.h>

#define NU 50000
#define NI 50000
#define NN 100000
#define NE 1600000
#define NP 200000
#define DIM 128
#define HID 64

// hist: 2 node ranges (100KB LDS each) x 64 edge chunks, one edge-array per kernel.
#define HR2 2
#define HC2 64
#define RN2 (NN / HR2)    // 50000 nodes per range
#define RNW2 (RN2 / 2)    // 25000 packed u16-pair words (100KB)
#define CE2 (NE / HC2)    // 25000 edges per chunk

// fill: 4 node ranges (100KB i32 cursor) x 64 chunks -> 256 blocks (full grid).
#define HRF 4
#define RNF (NN / HRF)    // 25000 nodes per range

typedef unsigned short bf16_t;
typedef __attribute__((ext_vector_type(8))) short short8;
typedef __attribute__((ext_vector_type(4))) float f32x4;
typedef __attribute__((ext_vector_type(2))) float f32x2;

__device__ __forceinline__ float bf2f(unsigned short u) {
  union { unsigned int i; float f; } c; c.i = ((unsigned int)u) << 16; return c.f;
}
__device__ __forceinline__ unsigned short f2bf(float f) {
  union { float f; unsigned int i; } c; c.f = f;
  unsigned int i = c.i;
  i += 0x7fffu + ((i >> 16) & 1u);   // RNE
  return (unsigned short)(i >> 16);
}
// packed bf16 pair -> f32x2 {lo, hi}; enables v_pk_add_f32 accumulate
__device__ __forceinline__ f32x2 unpack2(unsigned int w) {
  union { unsigned int i; float f; } lo, hi;
  lo.i = w << 16;
  hi.i = w & 0xffff0000u;
  f32x2 r; r.x = lo.f; r.y = hi.f;
  return r;
}
__device__ __forceinline__ int geti(const void* p, int i, bool i64) {
  return i64 ? (int)((const long long*)p)[i] : ((const int*)p)[i];
}

// ---------------- dtype probes ----------------
__global__ __launch_bounds__(64) void k_detect(const bf16_t* __restrict__ uf,
                                               const int* __restrict__ ei,
                                               int* __restrict__ flag) {
  int lane = threadIdx.x;
  float m = 0.f;
  for (int i = lane; i < 4096; i += 64) {
    float v = fabsf(bf2f(uf[i]));
    if (v < 3e38f) m = fmaxf(m, v);
  }
  int cnt = 0;
  for (int i = lane; i < 4096; i += 64) {
    if (ei[2 * i + 1] == 0) cnt++;
  }
  for (int off = 32; off > 0; off >>= 1) {
    m = fmaxf(m, __shfl_xor(m, off));
    cnt += __shfl_xor(cnt, off);
  }
  if (lane == 0) {
    flag[0] = (m > 100.f) ? 1 : 0;   // fp32 floats
    flag[1] = (cnt > 2048) ? 1 : 0;  // int64 ints
  }
}

// ---------------- single-array LDS histogram: per-(range,chunk) u16 counts ----------------
__global__ __launch_bounds__(1024) void k_hist1(const void* __restrict__ ev,
                                                const int* __restrict__ flag,
                                                unsigned int* __restrict__ part) {
  __shared__ unsigned int h[RNW2];   // 100 KB
  const bool i64 = (flag[1] != 0);
  int r = blockIdx.x & (HR2 - 1);
  int c = blockIdx.x >> 1;
  int lo = r * RN2, hiN = lo + RN2;
  int t = threadIdx.x;
  for (int i = t; i < RNW2; i += 1024) h[i] = 0u;
  __syncthreads();
  int ebeg = c * CE2;
  if (!i64) {
    const int* p = (const int*)ev + ebeg;
    for (int e = t * 4; e < CE2; e += 1024 * 4) {
      int4 v4 = *(const int4*)(p + e);
      int vv[4] = {v4.x, v4.y, v4.z, v4.w};
#pragma unroll
      for (int k = 0; k < 4; ++k) {
        int v = vv[k];
        if (v >= lo && v < hiN) {
          int loc = v - lo;
          atomicAdd(&h[loc >> 1], 1u << ((loc & 1) * 16));
        }
      }
    }
  } else {
    const long long* p = (const long long*)ev + ebeg;
    for (int e = t; e < CE2; e += 1024) {
      int v = (int)p[e];
      if (v >= lo && v < hiN) {
        int loc = v - lo;
        atomicAdd(&h[loc >> 1], 1u << ((loc & 1) * 16));
      }
    }
  }
  __syncthreads();
  unsigned int* po = part + c * (NN / 2) + (lo >> 1);
  for (int i = t; i < RNW2; i += 1024) po[i] = h[i];
}

// ---------------- reduce packed partials: totals + norms + u16 prefix + block sums ----------------
__global__ __launch_bounds__(256) void k_reduce(const unsigned int* __restrict__ pout,
                                                unsigned int* __restrict__ pin,
                                                int* __restrict__ din,
                                                float* __restrict__ onorm,
                                                float* __restrict__ inorm,
                                                int* __restrict__ bsums) {
  __shared__ int sh[256];
  int t = threadIdx.x;
  int w = blockIdx.x * 256 + t;
  unsigned int si0 = 0, si1 = 0;
  if (w < NN / 2) {
    unsigned int so0 = 0, so1 = 0;
#pragma unroll
    for (int c = 0; c < HC2; ++c) {
      unsigned int v = pout[c * (NN / 2) + w];
      so0 += v & 0xffffu;
      so1 += v >> 16;
    }
#pragma unroll
    for (int c = 0; c < HC2; ++c) {
      unsigned int v = pin[c * (NN / 2) + w];
      pin[c * (NN / 2) + w] = si0 | (si1 << 16);   // exclusive per-chunk offsets
      si0 += v & 0xffffu;
      si1 += v >> 16;
    }
    int n = 2 * w;
    din[n] = (int)si0;
    din[n + 1] = (int)si1;
    onorm[n] = rsqrtf((float)(so0 > 1u ? so0 : 1u));
    onorm[n + 1] = rsqrtf((float)(so1 > 1u ? so1 : 1u));
    inorm[n] = rsqrtf((float)(si0 > 1u ? si0 : 1u));
    inorm[n + 1] = rsqrtf((float)(si1 > 1u ? si1 : 1u));
  }
  sh[t] = (int)(si0 + si1);
  __syncthreads();
  for (int off = 128; off > 0; off >>= 1) {
    if (t < off) sh[t] += sh[t + off];
    __syncthreads();
  }
  if (t == 0) bsums[blockIdx.x] = sh[0];
}

__global__ __launch_bounds__(256) void k_scan2(const int* __restrict__ bsums,
                                               int* __restrict__ boffs, int nb) {
  __shared__ int sh[256];
  int t = threadIdx.x;
  int own = (t < nb) ? bsums[t] : 0;
  sh[t] = own;
  __syncthreads();
  for (int off = 1; off < 256; off <<= 1) {
    int add = (t >= off) ? sh[t - off] : 0;
    __syncthreads();
    sh[t] += add;
    __syncthreads();
  }
  if (t < nb) boffs[t] = sh[t] - own;
}

// 512 nodes per block (matches k_reduce block sums).
__global__ __launch_bounds__(256) void k_scan3(const int* __restrict__ in,
                                               const int* __restrict__ boffs,
                                               int* __restrict__ row_ptr,
                                               int* __restrict__ csr_src, int n) {
  __shared__ int sh[256];
  int t = threadIdx.x;
  int base = blockIdx.x * 512 + t * 2;
  int v0 = (base < n) ? in[base] : 0;
  int v1 = (base + 1 < n) ? in[base + 1] : 0;
  int s = v0 + v1;
  sh[t] = s;
  __syncthreads();
  for (int off = 1; off < 256; off <<= 1) {
    int add = (t >= off) ? sh[t - off] : 0;
    __syncthreads();
    sh[t] += add;
    __syncthreads();
  }
  int excl = boffs[blockIdx.x] + sh[t] - s;
  if (base < n) row_ptr[base] = excl;
  if (base + 1 < n) row_ptr[base + 1] = excl + v0;
  if (blockIdx.x == 0 && t == 0) row_ptr[n] = NE;
  // pad csr_src tail with zero-row index: gathers load csr_src[ee] unconditionally
  if (blockIdx.x == 0 && t < 32) csr_src[NE + t] = NN;
}

// ---------------- CSR fill via LDS cursors (zero global atomics), full grid ----------------
__global__ __launch_bounds__(1024) void k_fill2(const void* __restrict__ srcv,
                                                const void* __restrict__ dstv,
                                                const int* __restrict__ flag,
                                                const int* __restrict__ row_ptr,
                                                const unsigned int* __restrict__ pin,
                                                int* __restrict__ csr_src) {
  __shared__ int cur[RNF];   // 100 KB
  const bool i64 = (flag[1] != 0);
  int r = blockIdx.x & (HRF - 1);
  int c = blockIdx.x >> 2;
  int lo = r * RNF, hiN = lo + RNF;
  int t = threadIdx.x;
  const unsigned int* pw = pin + c * (NN / 2);
  const int* rp = row_ptr + lo;
  for (int i = t; i < RNF; i += 1024) {
    int node = lo + i;
    unsigned int wrd = pw[node >> 1];
    int off = (int)((wrd >> ((node & 1) * 16)) & 0xffffu);
    cur[i] = rp[i] + off;
  }
  __syncthreads();
  int ebeg = c * CE2;
  if (!i64) {
    const int* sp = (const int*)srcv + ebeg;
    const int* dp = (const int*)dstv + ebeg;
    for (int e = t * 4; e < CE2; e += 1024 * 4) {
      int4 dv = *(const int4*)(dp + e);
      int4 sv = *(const int4*)(sp + e);
      int dd[4] = {dv.x, dv.y, dv.z, dv.w};
      int ss[4] = {sv.x, sv.y, sv.z, sv.w};
#pragma unroll
      for (int k = 0; k < 4; ++k) {
        int d = dd[k];
        if (d >= lo && d < hiN) {
          int slot = atomicAdd(&cur[d - lo], 1);
          csr_src[slot] = ss[k];
        }
      }
    }
  } else {
    const long long* sp = (const long long*)srcv + ebeg;
    const long long* dp = (const long long*)dstv + ebeg;
    for (int e = t; e < CE2; e += 1024) {
      int d = (int)dp[e];
      if (d >= lo && d < hiN) {
        int slot = atomicAdd(&cur[d - lo], 1);
        csr_src[slot] = (int)sp[e];
      }
    }
  }
}

// ---------------- embed: relu(X@W+b) via MFMA (bf16) or VALU (f32 fallback) ----------------
// bf16 path: one wave = one 16-row tile; W staged TRANSPOSED in LDS (Wt[n][k], row
// pad 136) so B-fragments load as 16 ds_read_b128 per wave. fp32 out + bf16*onorm copy.
__global__ __launch_bounds__(256) void k_embed(const void* __restrict__ featv,
                                               const void* __restrict__ Wv,
                                               const void* __restrict__ biasv,
                                               const int* __restrict__ flag,
                                               const float* __restrict__ onorm_base,
                                               float* __restrict__ out,
                                               bf16_t* __restrict__ embs,
                                               bf16_t* __restrict__ zrow, int rows) {
  __shared__ __align__(16) char smem[DIM * HID * 4];  // 32 KB (union: Ws f32 | Wt bf16)
  __shared__ float bs[HID];
  const bool f32 = (flag[0] != 0);
  int t = threadIdx.x;
  if (zrow && blockIdx.x == 0 && t < 32)
    ((unsigned int*)zrow)[t] = 0u;   // zeros row at table index NN

  if (!f32) {
    // ---- MFMA path ----
    bf16_t* Wt = (bf16_t*)smem;                    // [HID][136] transposed, padded
    const bf16_t* W = (const bf16_t*)Wv;
    for (int i = t; i < DIM * HID; i += 256) {
      int k = i >> 6, n = i & 63;
      Wt[n * 136 + k] = W[i];
    }
    if (t < HID) bs[t] = bf2f(((const bf16_t*)biasv)[t]);
    __syncthreads();
    int wv = t >> 6;
    int lane = t & 63;
    int m = lane & 15;     // A row within tile / B col
    int q = lane >> 4;     // k-subchunk
    short8 Bf[4][4];
#pragma unroll
    for (int c = 0; c < 4; ++c)
#pragma unroll
      for (int nt = 0; nt < 4; ++nt)
        Bf[c][nt] = *(const short8*)&Wt[(nt * 16 + m) * 136 + c * 32 + q * 8];
    const bf16_t* feat = (const bf16_t*)featv;
    int tiles = rows >> 4;   // rows is a multiple of 16 (50000)
    for (int tile = blockIdx.x * 4 + wv; tile < tiles; tile += gridDim.x * 4) {
      const bf16_t* fr = feat + (size_t)(tile * 16 + m) * DIM + q * 8;
      short8 a0 = *(const short8*)(fr);
      short8 a1 = *(const short8*)(fr + 32);
      short8 a2 = *(const short8*)(fr + 64);
      short8 a3 = *(const short8*)(fr + 96);
      f32x4 acc[4];
#pragma unroll
      for (int nt = 0; nt < 4; ++nt) acc[nt] = (f32x4)(0.f);
#pragma unroll
      for (int nt = 0; nt < 4; ++nt) {
        acc[nt] = __builtin_amdgcn_mfma_f32_16x16x32_bf16(a0, Bf[0][nt], acc[nt], 0, 0, 0);
        acc[nt] = __builtin_amdgcn_mfma_f32_16x16x32_bf16(a1, Bf[1][nt], acc[nt], 0, 0, 0);
        acc[nt] = __builtin_amdgcn_mfma_f32_16x16x32_bf16(a2, Bf[2][nt], acc[nt], 0, 0, 0);
        acc[nt] = __builtin_amdgcn_mfma_f32_16x16x32_bf16(a3, Bf[3][nt], acc[nt], 0, 0, 0);
      }
      // epilogue: lane holds D[row=q*4+r][col=nt*16+m]
#pragma unroll
      for (int r = 0; r < 4; ++r) {
        int orow = tile * 16 + q * 4 + r;
        float sc = onorm_base[orow];
        float* orow_p = out + (size_t)orow * HID;
        bf16_t* erow_p = embs + (size_t)orow * HID;
#pragma unroll
        for (int nt = 0; nt < 4; ++nt) {
          int n = nt * 16 + m;
          float v = fmaxf(acc[nt][r] + bs[n], 0.f);
          orow_p[n] = v;
          erow_p[n] = f2bf(v * sc);
        }
      }
    }
    return;
  }

  // ---- f32 fallback (exact fp32 VALU path) ----
  float* Ws = (float*)smem;
  {
    const float* W = (const float*)Wv;
    for (int i = t; i < DIM * HID; i += 256) Ws[i] = W[i];
    if (t < HID) bs[t] = ((const float*)biasv)[t];
  }
  __syncthreads();
  int rl = t >> 4;
  int jq = t & 15;
  for (int rbase = blockIdx.x * 16; rbase < rows; rbase += gridDim.x * 16) {
    int row = rbase + rl;
    if (row >= rows) continue;
    float a0 = 0.f, a1 = 0.f, a2 = 0.f, a3 = 0.f;
    const float* fr = (const float*)featv + (size_t)row * DIM;
    for (int k0 = 0; k0 < DIM; k0 += 4) {
      float4 f4 = *(const float4*)(fr + k0);
      float fk[4] = {f4.x, f4.y, f4.z, f4.w};
#pragma unroll
      for (int kk = 0; kk < 4; ++kk) {
        const float* wr = &Ws[(k0 + kk) * HID + jq * 4];
        a0 += fk[kk] * wr[0];
        a1 += fk[kk] * wr[1];
        a2 += fk[kk] * wr[2];
        a3 += fk[kk] * wr[3];
      }
    }
    float4 r;
    r.x = fmaxf(a0 + bs[jq * 4 + 0], 0.f);
    r.y = fmaxf(a1 + bs[jq * 4 + 1], 0.f);
    r.z = fmaxf(a2 + bs[jq * 4 + 2], 0.f);
    r.w = fmaxf(a3 + bs[jq * 4 + 3], 0.f);
    *(float4*)&out[(size_t)row * HID + jq * 4] = r;
    float sc = onorm_base[row];
    uint2 p;
    p.x = (unsigned int)f2bf(r.x * sc) | ((unsigned int)f2bf(r.y * sc) << 16);
    p.y = (unsigned int)f2bf(r.z * sc) | ((unsigned int)f2bf(r.w * sc) << 16);
    *(uint2*)&embs[(size_t)row * HID + jq * 4] = p;
  }
}

// ---------------- gather layer 1: TWO nodes per wave ----------------
__global__ __launch_bounds__(256) void k_gather1(const bf16_t* __restrict__ embs,
                                                 const float* __restrict__ onorm,
                                                 const float* __restrict__ inorm,
                                                 const int* __restrict__ row_ptr,
                                                 const int* __restrict__ csr_src,
                                                 bf16_t* __restrict__ e1s) {
  if (blockIdx.x == 0 && threadIdx.x < 32)
    ((unsigned int*)(e1s + (size_t)NN * HID))[threadIdx.x] = 0u;  // e1s zeros row
  int lane = threadIdx.x & 63;
  int h = lane >> 5;            // node sub-id within wave
  int g = (lane >> 3) & 3;      // 4 edge-groups
  int l8 = (lane & 7) * 8;      // column base (8 bf16 = 16B per lane)
  int n = blockIdx.x * 8 + (threadIdx.x >> 6) * 2 + h;
  int beg = row_ptr[n], end = row_ptr[n + 1];
  f32x2 a[4];
#pragma unroll
  for (int j = 0; j < 4; ++j) a[j] = (f32x2)(0.f);
  for (int base = beg; base < end; base += 16) {
    int sv[4];
#pragma unroll
    for (int k = 0; k < 4; ++k) {
      int ee = base + k * 4 + g;
      int raw = csr_src[ee];          // always in-bounds (32-entry pad)
      sv[k] = (ee < end) ? raw : NN;  // tail -> zeros row
    }
#pragma unroll
    for (int k = 0; k < 4; ++k) {
      uint4 u = *(const uint4*)(embs + (sv[k] << 6) + l8);
      a[0] += unpack2(u.x);
      a[1] += unpack2(u.y);
      a[2] += unpack2(u.z);
      a[3] += unpack2(u.w);
    }
  }
#pragma unroll
  for (int j = 0; j < 4; ++j) {    // reduce over g (stays within half-wave)
    a[j].x += __shfl_xor(a[j].x, 8);
    a[j].y += __shfl_xor(a[j].y, 8);
    a[j].x += __shfl_xor(a[j].x, 16);
    a[j].y += __shfl_xor(a[j].y, 16);
  }
  if (g == 0) {
    float sc = inorm[n] * onorm[n];   // pre-scale for next gather
    uint4 p;
    p.x = (unsigned int)f2bf(a[0].x * sc) | ((unsigned int)f2bf(a[0].y * sc) << 16);
    p.y = (unsigned int)f2bf(a[1].x * sc) | ((unsigned int)f2bf(a[1].y * sc) << 16);
    p.z = (unsigned int)f2bf(a[2].x * sc) | ((unsigned int)f2bf(a[2].y * sc) << 16);
    p.w = (unsigned int)f2bf(a[3].x * sc) | ((unsigned int)f2bf(a[3].y * sc) << 16);
    *(uint4*)(e1s + (size_t)n * HID + l8) = p;
  }
}

// ---------------- gather layer 2 + combine + side; TWO nodes per wave ----------------
__global__ __launch_bounds__(256) void k_gather2c(float* __restrict__ emb0,
                                                  const bf16_t* __restrict__ e1s,
                                                  const void* __restrict__ sidev,
                                                  const int* __restrict__ flag,
                                                  const float* __restrict__ onorm,
                                                  const float* __restrict__ inorm,
                                                  const int* __restrict__ row_ptr,
                                                  const int* __restrict__ csr_src,
                                                  bf16_t* __restrict__ fin_bf) {
  int lane = threadIdx.x & 63;
  int h = lane >> 5;
  int g = (lane >> 3) & 3;
  int l8 = (lane & 7) * 8;
  int n = blockIdx.x * 8 + (threadIdx.x >> 6) * 2 + h;
  int beg = row_ptr[n], end = row_ptr[n + 1];
  f32x2 a[4];
#pragma unroll
  for (int j = 0; j < 4; ++j) a[j] = (f32x2)(0.f);
  for (int base = beg; base < end; base += 16) {
    int sv[4];
#pragma unroll
    for (int k = 0; k < 4; ++k) {
      int ee = base + k * 4 + g;
      int raw = csr_src[ee];
      sv[k] = (ee < end) ? raw : NN;
    }
#pragma unroll
    for (int k = 0; k < 4; ++k) {
      uint4 u = *(const uint4*)(e1s + (sv[k] << 6) + l8);
      a[0] += unpack2(u.x);
      a[1] += unpack2(u.y);
      a[2] += unpack2(u.z);
      a[3] += unpack2(u.w);
    }
  }
#pragma unroll
  for (int j = 0; j < 4; ++j) {
    a[j].x += __shfl_xor(a[j].x, 8);
    a[j].y += __shfl_xor(a[j].y, 8);
    a[j].x += __shfl_xor(a[j].x, 16);
    a[j].y += __shfl_xor(a[j].y, 16);
  }
  if (g == 0) {
    float aa[8] = {a[0].x, a[0].y, a[1].x, a[1].y, a[2].x, a[2].y, a[3].x, a[3].y};
    float inorm_n = inorm[n];
    float inv_on = 1.0f / onorm[n];     // e1 = e1s / onorm
    size_t off = (size_t)n * HID + l8;
    uint4 u = *(const uint4*)(e1s + off);
    unsigned int w[4] = {u.x, u.y, u.z, u.w};
    float e1v[8];
#pragma unroll
    for (int j = 0; j < 4; ++j) {
      e1v[2 * j]     = bf2f((unsigned short)(w[j] & 0xffffu)) * inv_on;
      e1v[2 * j + 1] = bf2f((unsigned short)(w[j] >> 16)) * inv_on;
    }
    float4 b0 = *(const float4*)&emb0[off];
    float4 b1 = *(const float4*)&emb0[off + 4];
    float bb[8] = {b0.x, b0.y, b0.z, b0.w, b1.x, b1.y, b1.z, b1.w};
    const float s2 = 1.f / 3.f;
    float vv[8];
#pragma unroll
    for (int j = 0; j < 8; ++j)
      vv[j] = bb[j] + 0.5f * e1v[j] + s2 * aa[j] * inorm_n;
    if (n >= NU) {
      size_t soff = (size_t)(n - NU) * HID + l8;
      if (flag[0] != 0) {
        float4 s0 = *(const float4*)((const float*)sidev + soff);
        float4 s1 = *(const float4*)((const float*)sidev + soff + 4);
        vv[0] += s0.x; vv[1] += s0.y; vv[2] += s0.z; vv[3] += s0.w;
        vv[4] += s1.x; vv[5] += s1.y; vv[6] += s1.z; vv[7] += s1.w;
      } else {
        uint4 su = *(const uint4*)((const bf16_t*)sidev + soff);
        unsigned int sw[4] = {su.x, su.y, su.z, su.w};
#pragma unroll
        for (int j = 0; j < 4; ++j) {
          vv[2 * j]     += bf2f((unsigned short)(sw[j] & 0xffffu));
          vv[2 * j + 1] += bf2f((unsigned short)(sw[j] >> 16));
        }
      }
    }
    float4 o0, o1;
    o0.x = vv[0]; o0.y = vv[1]; o0.z = vv[2]; o0.w = vv[3];
    o1.x = vv[4]; o1.y = vv[5]; o1.z = vv[6]; o1.w = vv[7];
    *(float4*)&emb0[off] = o0;
    *(float4*)&emb0[off + 4] = o1;
    uint4 pb;
    pb.x = (unsigned int)f2bf(vv[0]) | ((unsigned int)f2bf(vv[1]) << 16);
    pb.y = (unsigned int)f2bf(vv[2]) | ((unsigned int)f2bf(vv[3]) << 16);
    pb.z = (unsigned int)f2bf(vv[4]) | ((unsigned int)f2bf(vv[5]) << 16);
    pb.w = (unsigned int)f2bf(vv[6]) | ((unsigned int)f2bf(vv[7]) << 16);
    *(uint4*)(fin_bf + off) = pb;
  }
}

// ---------------- decode via MFMA, pos/neg fused, 2-deep software pipeline ----------------
__global__ __launch_bounds__(256) void k_decode(const bf16_t* __restrict__ zb,  // fin_bf
                                                const void* __restrict__ W1v,
                                                const void* __restrict__ b1v,
                                                const void* __restrict__ W2v,
                                                const void* __restrict__ Tfv,
                                                const void* __restrict__ Tcfv,
                                                const int* __restrict__ flag,
                                                const void* __restrict__ userId,
                                                const void* __restrict__ posId,
                                                const void* __restrict__ negId,
                                                float* __restrict__ out_lf,
                                                float* __restrict__ out_lcf) {
  __shared__ bf16_t W1b[128 * 65];   // padded rows (65) to dodge LDS bank conflicts
  __shared__ float wlast[HID], b1s[HID], W2s[HID];
  const bool f32 = (flag[0] != 0);
  const bool i64 = (flag[1] != 0);
  int t = threadIdx.x;
  if (f32) {
    const float* W1 = (const float*)W1v;
    for (int i = t; i < 128 * 64; i += 256) W1b[(i >> 6) * 65 + (i & 63)] = f2bf(W1[i]);
    if (t < HID) {
      wlast[t] = W1[128 * 64 + t];
      b1s[t] = ((const float*)b1v)[t];
      W2s[t] = ((const float*)W2v)[t];
    }
  } else {
    const bf16_t* W1 = (const bf16_t*)W1v;
    for (int i = t; i < 128 * 64; i += 256) W1b[(i >> 6) * 65 + (i & 63)] = W1[i];
    if (t < HID) {
      wlast[t] = bf2f(W1[128 * 64 + t]);
      b1s[t] = bf2f(((const bf16_t*)b1v)[t]);
      W2s[t] = bf2f(((const bf16_t*)W2v)[t]);
    }
  }
  __syncthreads();
  int wv = t >> 6;
  int lane = t & 63;
  int m = lane & 15;     // A row within tile / B col
  int q = lane >> 4;     // k-subchunk
  short8 Bf[4][4];
#pragma unroll
  for (int c = 0; c < 4; ++c)
#pragma unroll
    for (int nt = 0; nt < 4; ++nt)
#pragma unroll
      for (int j = 0; j < 8; ++j)
        Bf[c][nt][j] = (short)W1b[(c * 32 + q * 8 + j) * 65 + nt * 16 + m];

  const int tiles = NP / 16;  // 12500 pair-tiles
  const int stride = gridDim.x * 4;
  int tile = blockIdx.x * 4 + wv;
  if (tile >= tiles) return;

  // prologue: load first tile's ids + fragments
  int pid = tile * 16 + m;
  int uid = geti(userId, pid, i64);
  int pidx = geti(posId, pid, i64);
  int nidx = geti(negId, pid, i64);
  const bf16_t* ur = zb + (size_t)uid * HID;
  const bf16_t* pr = zb + (size_t)(NU + pidx) * HID;
  const bf16_t* nr = zb + (size_t)(NU + nidx) * HID;
  short8 au0 = *(const short8*)(ur + q * 8);
  short8 au1 = *(const short8*)(ur + 32 + q * 8);
  short8 ap0 = *(const short8*)(pr + q * 8);
  short8 ap1 = *(const short8*)(pr + 32 + q * 8);
  short8 an0 = *(const short8*)(nr + q * 8);
  short8 an1 = *(const short8*)(nr + 32 + q * 8);

  while (true) {
    int ntile = tile + stride;
    bool have_next = (ntile < tiles);
    int uid2 = 0, pidx2 = 0, nidx2 = 0;
    if (have_next) {               // issue next ids early (hide under MFMA)
      int pid2 = ntile * 16 + m;
      uid2 = geti(userId, pid2, i64);
      pidx2 = geti(posId, pid2, i64);
      nidx2 = geti(negId, pid2, i64);
    }
    // T values for current tile
    float tf_p[4], tc_p[4], tf_n[4], tc_n[4];
    int rbase = tile * 16 + q * 4;
    if (f32) {
      float4 t4 = *(const float4*)((const float*)Tfv + rbase);
      float4 c4 = *(const float4*)((const float*)Tcfv + rbase);
      float4 t4n = *(const float4*)((const float*)Tfv + rbase + NP);
      float4 c4n = *(const float4*)((const float*)Tcfv + rbase + NP);
      tf_p[0] = t4.x; tf_p[1] = t4.y; tf_p[2] = t4.z; tf_p[3] = t4.w;
      tc_p[0] = c4.x; tc_p[1] = c4.y; tc_p[2] = c4.z; tc_p[3] = c4.w;
      tf_n[0] = t4n.x; tf_n[1] = t4n.y; tf_n[2] = t4n.z; tf_n[3] = t4n.w;
      tc_n[0] = c4n.x; tc_n[1] = c4n.y; tc_n[2] = c4n.z; tc_n[3] = c4n.w;
    } else {
      const bf16_t* tp = (const bf16_t*)Tfv + rbase;
      const bf16_t* cp = (const bf16_t*)Tcfv + rbase;
#pragma unroll
      for (int r = 0; r < 4; ++r) {
        tf_p[r] = bf2f(tp[r]); tc_p[r] = bf2f(cp[r]);
        tf_n[r] = bf2f(tp[r + NP]); tc_n[r] = bf2f(cp[r + NP]);
      }
    }
    // MFMA + streaming epilogue accumulation (per-nt, same order as before)
    float sfp[4], scp[4], sfn[4], scn[4];
#pragma unroll
    for (int r = 0; r < 4; ++r) { sfp[r] = 0.f; scp[r] = 0.f; sfn[r] = 0.f; scn[r] = 0.f; }
#pragma unroll
    for (int nt = 0; nt < 4; ++nt) {
      f32x4 accu = (f32x4)(0.f);
      accu = __builtin_amdgcn_mfma_f32_16x16x32_bf16(au0, Bf[0][nt], accu, 0, 0, 0);
      accu = __builtin_amdgcn_mfma_f32_16x16x32_bf16(au1, Bf[1][nt], accu, 0, 0, 0);
      f32x4 accp = __builtin_amdgcn_mfma_f32_16x16x32_bf16(ap0, Bf[2][nt], accu, 0, 0, 0);
      accp = __builtin_amdgcn_mfma_f32_16x16x32_bf16(ap1, Bf[3][nt], accp, 0, 0, 0);
      f32x4 accn = __builtin_amdgcn_mfma_f32_16x16x32_bf16(an0, Bf[2][nt], accu, 0, 0, 0);
      accn = __builtin_amdgcn_mfma_f32_16x16x32_bf16(an1, Bf[3][nt], accn, 0, 0, 0);
      int n = nt * 16 + m;
      float b = b1s[n];
      float wl = wlast[n];
      float w2 = W2s[n];
#pragma unroll
      for (int r = 0; r < 4; ++r) {
        float xp = accp[r] + b;
        float xn = accn[r] + b;
        float v0 = xp + tf_p[r] * wl;
        float v1 = xp + tc_p[r] * wl;
        float v2 = xn + tf_n[r] * wl;
        float v3 = xn + tc_n[r] * wl;
        sfp[r] += (v0 > 0.f ? v0 : (__expf(v0) - 1.f)) * w2;
        scp[r] += (v1 > 0.f ? v1 : (__expf(v1) - 1.f)) * w2;
        sfn[r] += (v2 > 0.f ? v2 : (__expf(v2) - 1.f)) * w2;
        scn[r] += (v3 > 0.f ? v3 : (__expf(v3) - 1.f)) * w2;
      }
    }
    // issue next tile's fragment loads now; latency hides under shuffle reduce below
    short8 bu0 = au0, bu1 = au1, bp0 = ap0, bp1 = ap1, bn0 = an0, bn1 = an1;
    if (have_next) {
      const bf16_t* ur2 = zb + (size_t)uid2 * HID;
      const bf16_t* pr2 = zb + (size_t)(NU + pidx2) * HID;
      const bf16_t* nr2 = zb + (size_t)(NU + nidx2) * HID;
      bu0 = *(const short8*)(ur2 + q * 8);
      bu1 = *(const short8*)(ur2 + 32 + q * 8);
      bp0 = *(const short8*)(pr2 + q * 8);
      bp1 = *(const short8*)(pr2 + 32 + q * 8);
      bn0 = *(const short8*)(nr2 + q * 8);
      bn1 = *(const short8*)(nr2 + 32 + q * 8);
    }
#pragma unroll
    for (int r = 0; r < 4; ++r) {
#pragma unroll
      for (int s = 1; s < 16; s <<= 1) {
        sfp[r] += __shfl_xor(sfp[r], s);
        scp[r] += __shfl_xor(scp[r], s);
        sfn[r] += __shfl_xor(sfn[r], s);
        scn[r] += __shfl_xor(scn[r], s);
      }
      if (m == 0) {
        int pr2i = rbase + r;
        out_lf[pr2i] = sfp[r];
        out_lcf[pr2i] = scp[r];
        out_lf[pr2i + NP] = sfn[r];
        out_lcf[pr2i + NP] = scn[r];
      }
    }
    if (!have_next) break;
    tile = ntile;
    au0 = bu0; au1 = bu1; ap0 = bp0; ap1 = bp1; an0 = bn0; an1 = bn1;
  }
}

extern "C" void kernel_launch(void* const* d_in, const int* in_sizes, int n_in,
                              void* d_out, int out_size, void* d_ws, size_t ws_size,
                              hipStream_t stream) {
  (void)in_sizes; (void)n_in; (void)out_size;
  const void* user_f = d_in[0];
  const void* item_f = d_in[1];
  const void* side   = d_in[2];
  const void* Tf     = d_in[3];
  const void* Tcf    = d_in[4];
  const void* Wu     = d_in[5];
  const void* bu     = d_in[6];
  const void* Wi     = d_in[7];
  const void* bi     = d_in[8];
  const void* W1     = d_in[9];
  const void* b1     = d_in[10];
  const void* W2     = d_in[11];
  const void* esrc   = d_in[12];
  const void* edst   = d_in[13];
  const void* userId = d_in[14];
  const void* posId  = d_in[15];
  const void* negId  = d_in[16];

  const size_t WS_NEEDED = 33602688;
  if (ws_size < WS_NEEDED) return;

  char* ws = (char*)d_ws;
  int*   deg_in  = (int*)(ws + 0);             // 400000
  float* onorm   = (float*)(ws + 400000);      // 400000
  float* inorm   = (float*)(ws + 800000);      // 400000
  int*   row_ptr = (int*)(ws + 1200000);       // 400128 (NN+1 ints, padded)
  int*   bsums   = (int*)(ws + 1600128);       // 1024 (196 ints)
  int*   boffs   = (int*)(ws + 1601152);       // 1024
  int*   flag    = (int*)(ws + 1602176);       // 128
  int*   csr_src = (int*)(ws + 1602304);       // 6.4 MB + 128B pad (NE+32 ints)
  // partial histograms overlay embs/e1s (dead before embed/gather writes):
  unsigned int* pout = (unsigned int*)(ws + 8002432);   // 12.8 MB: [HC2][NN/2] u16-packed
  unsigned int* pin  = (unsigned int*)(ws + 20802560);  // 12.8 MB: ditto -> prefixes
  bf16_t* embs   = (bf16_t*)(ws + 8002432);    // (NN+1) rows bf16; later reused as fin_bf
  bf16_t* e1s    = (bf16_t*)(ws + 20802560);   // (NN+1) rows bf16
  bf16_t* fin_bf = embs;                       // embs dead after k_gather1 (stream-ordered)

  float* out     = (float*)d_out;
  float* emb0    = out;
  float* out_lf  = out + (size_t)NN * HID;
  float* out_lcf = out_lf + 2 * NP;

  k_detect<<<1, 64, 0, stream>>>((const bf16_t*)user_f, (const int*)esrc, flag);
  k_hist1<<<HR2 * HC2, 1024, 0, stream>>>(esrc, flag, pout);
  k_hist1<<<HR2 * HC2, 1024, 0, stream>>>(edst, flag, pin);
  k_reduce<<<196, 256, 0, stream>>>(pout, pin, deg_in, onorm, inorm, bsums);
  k_scan2<<<1, 256, 0, stream>>>(bsums, boffs, 196);
  k_scan3<<<196, 256, 0, stream>>>(deg_in, boffs, row_ptr, csr_src, NN);
  k_fill2<<<HRF * HC2, 1024, 0, stream>>>(esrc, edst, flag, row_ptr, pin, csr_src);
  k_embed<<<512, 256, 0, stream>>>(user_f, Wu, bu, flag, onorm, emb0, embs,
                                   embs + (size_t)NN * HID, NU);
  k_embed<<<512, 256, 0, stream>>>(item_f, Wi, bi, flag, onorm + NU,
                                   emb0 + (size_t)NU * HID, embs + (size_t)NU * HID,
                                   (bf16_t*)0, NI);
  k_gather1<<<NN / 8, 256, 0, stream>>>(embs, onorm, inorm, row_ptr, csr_src, e1s);
  k_gather2c<<<NN / 8, 256, 0, stream>>>(emb0, e1s, side, flag, onorm, inorm, row_ptr,
                                         csr_src, fin_bf);
  k_decode<<<1024, 256, 0, stream>>>(fin_bf, W1, b1, W2, Tf, Tcf, flag,
                                     userId, posId, negId, out_lf, out_lcf);
}

// Round 9
// 355.939 us; speedup vs baseline: 1.1266x; 1.0868x over previous
//
#include <hip/hip_runtime.h>

#define NU 50000
#define NI 50000
#define NN 100000
#define NE 1600000
#define NP 200000
#define DIM 128
#define HID 64

// hist: 2 node ranges (100KB LDS each) x 64 edge chunks x 2 arrays -> 256 blocks.
#define HR2 2
#define HC2 64
#define RN2 (NN / HR2)    // 50000 nodes per range
#define RNW2 (RN2 / 2)    // 25000 packed u16-pair words (100KB)
#define CE2 (NE / HC2)    // 25000 edges per chunk

// fill: 4 node ranges (100KB i32 cursor) x 64 chunks -> 256 blocks (full grid).
#define HRF 4
#define RNF (NN / HRF)    // 25000 nodes per range

#define ZROFF (NN * HID)  // element offset of the zeros row

typedef unsigned short bf16_t;
typedef __attribute__((ext_vector_type(8))) short short8;
typedef __attribute__((ext_vector_type(4))) float f32x4;
typedef __attribute__((ext_vector_type(2))) float f32x2;

__device__ __forceinline__ float bf2f(unsigned short u) {
  union { unsigned int i; float f; } c; c.i = ((unsigned int)u) << 16; return c.f;
}
__device__ __forceinline__ unsigned short f2bf(float f) {
  union { float f; unsigned int i; } c; c.f = f;
  unsigned int i = c.i;
  i += 0x7fffu + ((i >> 16) & 1u);   // RNE
  return (unsigned short)(i >> 16);
}
// packed bf16 pair -> f32x2 {lo, hi}; enables v_pk_add_f32 accumulate
__device__ __forceinline__ f32x2 unpack2(unsigned int w) {
  union { unsigned int i; float f; } lo, hi;
  lo.i = w << 16;
  hi.i = w & 0xffff0000u;
  f32x2 r; r.x = lo.f; r.y = hi.f;
  return r;
}
__device__ __forceinline__ int geti(const void* p, int i, bool i64) {
  return i64 ? (int)((const long long*)p)[i] : ((const int*)p)[i];
}

// ---------------- dtype probes (1024 samples; still statistically certain) ----------------
__global__ __launch_bounds__(64) void k_detect(const bf16_t* __restrict__ uf,
                                               const int* __restrict__ ei,
                                               int* __restrict__ flag) {
  int lane = threadIdx.x;
  float m = 0.f;
  for (int i = lane; i < 1024; i += 64) {
    float v = fabsf(bf2f(uf[i]));
    if (v < 3e38f) m = fmaxf(m, v);
  }
  int cnt = 0;
  for (int i = lane; i < 1024; i += 64) {
    if (ei[2 * i + 1] == 0) cnt++;
  }
  for (int off = 32; off > 0; off >>= 1) {
    m = fmaxf(m, __shfl_xor(m, off));
    cnt += __shfl_xor(cnt, off);
  }
  if (lane == 0) {
    flag[0] = (m > 100.f) ? 1 : 0;   // fp32 floats
    flag[1] = (cnt > 512) ? 1 : 0;   // int64 ints
  }
}

// ---------------- merged LDS histogram: both edge arrays, 256 blocks ----------------
// block b: array = b>>7 (0=src->pout, 1=dst->pin); sub = b&127: r = sub&1, c = sub>>1.
// Per-chunk counts <= 25000 fit u16; packed-pair carries cannot cross.
__global__ __launch_bounds__(1024) void k_hist2(const void* __restrict__ srcv,
                                                const void* __restrict__ dstv,
                                                const int* __restrict__ flag,
                                                unsigned int* __restrict__ pout,
                                                unsigned int* __restrict__ pin) {
  __shared__ unsigned int h[RNW2];   // 100 KB
  const bool i64 = (flag[1] != 0);
  int arr = blockIdx.x >> 7;
  int sub = blockIdx.x & 127;
  const void* ev = arr ? dstv : srcv;
  unsigned int* part = arr ? pin : pout;
  int r = sub & (HR2 - 1);
  int c = sub >> 1;
  int lo = r * RN2, hiN = lo + RN2;
  int t = threadIdx.x;
  for (int i = t; i < RNW2; i += 1024) h[i] = 0u;
  __syncthreads();
  int ebeg = c * CE2;
  if (!i64) {
    const int* p = (const int*)ev + ebeg;
    for (int e = t * 4; e < CE2; e += 1024 * 4) {
      int4 v4 = *(const int4*)(p + e);
      int vv[4] = {v4.x, v4.y, v4.z, v4.w};
#pragma unroll
      for (int k = 0; k < 4; ++k) {
        int v = vv[k];
        if (v >= lo && v < hiN) {
          int loc = v - lo;
          atomicAdd(&h[loc >> 1], 1u << ((loc & 1) * 16));
        }
      }
    }
  } else {
    const long long* p = (const long long*)ev + ebeg;
    for (int e = t; e < CE2; e += 1024) {
      int v = (int)p[e];
      if (v >= lo && v < hiN) {
        int loc = v - lo;
        atomicAdd(&h[loc >> 1], 1u << ((loc & 1) * 16));
      }
    }
  }
  __syncthreads();
  unsigned int* po = part + c * (NN / 2) + (lo >> 1);
  for (int i = t; i < RNW2; i += 1024) po[i] = h[i];
}

// ---------------- reduce packed partials: totals + norms + u16 prefix + block sums ----------------
__global__ __launch_bounds__(256) void k_reduce(const unsigned int* __restrict__ pout,
                                                unsigned int* __restrict__ pin,
                                                int* __restrict__ din,
                                                float* __restrict__ onorm,
                                                float* __restrict__ inorm,
                                                int* __restrict__ bsums) {
  __shared__ int sh[256];
  int t = threadIdx.x;
  int w = blockIdx.x * 256 + t;
  unsigned int si0 = 0, si1 = 0;
  if (w < NN / 2) {
    unsigned int so0 = 0, so1 = 0;
#pragma unroll
    for (int c = 0; c < HC2; ++c) {
      unsigned int v = pout[c * (NN / 2) + w];
      so0 += v & 0xffffu;
      so1 += v >> 16;
    }
#pragma unroll
    for (int c = 0; c < HC2; ++c) {
      unsigned int v = pin[c * (NN / 2) + w];
      pin[c * (NN / 2) + w] = si0 | (si1 << 16);   // exclusive per-chunk offsets
      si0 += v & 0xffffu;
      si1 += v >> 16;
    }
    int n = 2 * w;
    din[n] = (int)si0;
    din[n + 1] = (int)si1;
    onorm[n] = rsqrtf((float)(so0 > 1u ? so0 : 1u));
    onorm[n + 1] = rsqrtf((float)(so1 > 1u ? so1 : 1u));
    inorm[n] = rsqrtf((float)(si0 > 1u ? si0 : 1u));
    inorm[n + 1] = rsqrtf((float)(si1 > 1u ? si1 : 1u));
  }
  sh[t] = (int)(si0 + si1);
  __syncthreads();
  for (int off = 128; off > 0; off >>= 1) {
    if (t < off) sh[t] += sh[t + off];
    __syncthreads();
  }
  if (t == 0) bsums[blockIdx.x] = sh[0];
}

__global__ __launch_bounds__(256) void k_scan2(const int* __restrict__ bsums,
                                               int* __restrict__ boffs, int nb) {
  __shared__ int sh[256];
  int t = threadIdx.x;
  int own = (t < nb) ? bsums[t] : 0;
  sh[t] = own;
  __syncthreads();
  for (int off = 1; off < 256; off <<= 1) {
    int add = (t >= off) ? sh[t - off] : 0;
    __syncthreads();
    sh[t] += add;
    __syncthreads();
  }
  if (t < nb) boffs[t] = sh[t] - own;
}

// 512 nodes per block (matches k_reduce block sums).
__global__ __launch_bounds__(256) void k_scan3(const int* __restrict__ in,
                                               const int* __restrict__ boffs,
                                               int* __restrict__ row_ptr,
                                               int* __restrict__ csr_src, int n) {
  __shared__ int sh[256];
  int t = threadIdx.x;
  int base = blockIdx.x * 512 + t * 2;
  int v0 = (base < n) ? in[base] : 0;
  int v1 = (base + 1 < n) ? in[base + 1] : 0;
  int s = v0 + v1;
  sh[t] = s;
  __syncthreads();
  for (int off = 1; off < 256; off <<= 1) {
    int add = (t >= off) ? sh[t - off] : 0;
    __syncthreads();
    sh[t] += add;
    __syncthreads();
  }
  int excl = boffs[blockIdx.x] + sh[t] - s;
  if (base < n) row_ptr[base] = excl;
  if (base + 1 < n) row_ptr[base + 1] = excl + v0;
  if (blockIdx.x == 0 && t == 0) row_ptr[n] = NE;
  // pad csr_src tail with zeros-row ELEMENT OFFSET: gathers load csr_src[ee] unconditionally
  if (blockIdx.x == 0 && t < 32) csr_src[NE + t] = ZROFF;
}

// ---------------- CSR fill via LDS cursors (zero global atomics), full grid ----------------
// csr_src entries are PRE-SHIFTED element offsets (node*HID) -> no shift in gathers.
__global__ __launch_bounds__(1024) void k_fill2(const void* __restrict__ srcv,
                                                const void* __restrict__ dstv,
                                                const int* __restrict__ flag,
                                                const int* __restrict__ row_ptr,
                                                const unsigned int* __restrict__ pin,
                                                int* __restrict__ csr_src) {
  __shared__ int cur[RNF];   // 100 KB
  const bool i64 = (flag[1] != 0);
  int r = blockIdx.x & (HRF - 1);
  int c = blockIdx.x >> 2;
  int lo = r * RNF, hiN = lo + RNF;
  int t = threadIdx.x;
  const unsigned int* pw = pin + c * (NN / 2);
  const int* rp = row_ptr + lo;
  for (int i = t; i < RNF; i += 1024) {
    int node = lo + i;
    unsigned int wrd = pw[node >> 1];
    int off = (int)((wrd >> ((node & 1) * 16)) & 0xffffu);
    cur[i] = rp[i] + off;
  }
  __syncthreads();
  int ebeg = c * CE2;
  if (!i64) {
    const int* sp = (const int*)srcv + ebeg;
    const int* dp = (const int*)dstv + ebeg;
    for (int e = t * 4; e < CE2; e += 1024 * 4) {
      int4 dv = *(const int4*)(dp + e);
      int4 sv = *(const int4*)(sp + e);
      int dd[4] = {dv.x, dv.y, dv.z, dv.w};
      int ss[4] = {sv.x, sv.y, sv.z, sv.w};
#pragma unroll
      for (int k = 0; k < 4; ++k) {
        int d = dd[k];
        if (d >= lo && d < hiN) {
          int slot = atomicAdd(&cur[d - lo], 1);
          csr_src[slot] = ss[k] << 6;   // element offset (node*HID)
        }
      }
    }
  } else {
    const long long* sp = (const long long*)srcv + ebeg;
    const long long* dp = (const long long*)dstv + ebeg;
    for (int e = t; e < CE2; e += 1024) {
      int d = (int)dp[e];
      if (d >= lo && d < hiN) {
        int slot = atomicAdd(&cur[d - lo], 1);
        csr_src[slot] = ((int)sp[e]) << 6;
      }
    }
  }
}

// ---------------- merged embed: users (blocks 0-511) + items (blocks 512-1023) ----------------
// relu(X@W+b) via MFMA (bf16) or VALU (f32 fallback); fp32 out + bf16*onorm copy.
#define EMB_HALF 512
__global__ __launch_bounds__(256) void k_embed2(const void* __restrict__ uFv,
                                                const void* __restrict__ iFv,
                                                const void* __restrict__ Wuv,
                                                const void* __restrict__ buv,
                                                const void* __restrict__ Wiv,
                                                const void* __restrict__ biv,
                                                const int* __restrict__ flag,
                                                const float* __restrict__ onorm,
                                                float* __restrict__ out,
                                                bf16_t* __restrict__ embs) {
  __shared__ __align__(16) char smem[DIM * HID * 4];  // 32 KB (union: Ws f32 | Wt bf16)
  __shared__ float bs[HID];
  const bool f32 = (flag[0] != 0);
  int t = threadIdx.x;
  const bool item = (blockIdx.x >= EMB_HALF);
  int bx = item ? (int)blockIdx.x - EMB_HALF : (int)blockIdx.x;
  const void* featv = item ? iFv : uFv;
  const void* Wv = item ? Wiv : Wuv;
  const void* biasv = item ? biv : buv;
  int row0 = item ? NU : 0;
  const int rows = NU;   // == NI
  const float* onorm_base = onorm + row0;
  float* out_b = out + (size_t)row0 * HID;
  bf16_t* embs_b = embs + (size_t)row0 * HID;
  if (blockIdx.x == 0 && t < 32)
    ((unsigned int*)(embs + (size_t)NN * HID))[t] = 0u;   // zeros row at table index NN

  if (!f32) {
    // ---- MFMA path ----
    bf16_t* Wt = (bf16_t*)smem;                    // [HID][136] transposed, padded
    const bf16_t* W = (const bf16_t*)Wv;
    for (int i = t; i < DIM * HID; i += 256) {
      int k = i >> 6, n = i & 63;
      Wt[n * 136 + k] = W[i];
    }
    if (t < HID) bs[t] = bf2f(((const bf16_t*)biasv)[t]);
    __syncthreads();
    int wv = t >> 6;
    int lane = t & 63;
    int m = lane & 15;     // A row within tile / B col
    int q = lane >> 4;     // k-subchunk
    short8 Bf[4][4];
#pragma unroll
    for (int c = 0; c < 4; ++c)
#pragma unroll
      for (int nt = 0; nt < 4; ++nt)
        Bf[c][nt] = *(const short8*)&Wt[(nt * 16 + m) * 136 + c * 32 + q * 8];
    const bf16_t* feat = (const bf16_t*)featv;
    int tiles = rows >> 4;   // 3125
    for (int tile = bx * 4 + wv; tile < tiles; tile += EMB_HALF * 4) {
      const bf16_t* fr = feat + (size_t)(tile * 16 + m) * DIM + q * 8;
      short8 a0 = *(const short8*)(fr);
      short8 a1 = *(const short8*)(fr + 32);
      short8 a2 = *(const short8*)(fr + 64);
      short8 a3 = *(const short8*)(fr + 96);
      f32x4 acc[4];
#pragma unroll
      for (int nt = 0; nt < 4; ++nt) acc[nt] = (f32x4)(0.f);
#pragma unroll
      for (int nt = 0; nt < 4; ++nt) {
        acc[nt] = __builtin_amdgcn_mfma_f32_16x16x32_bf16(a0, Bf[0][nt], acc[nt], 0, 0, 0);
        acc[nt] = __builtin_amdgcn_mfma_f32_16x16x32_bf16(a1, Bf[1][nt], acc[nt], 0, 0, 0);
        acc[nt] = __builtin_amdgcn_mfma_f32_16x16x32_bf16(a2, Bf[2][nt], acc[nt], 0, 0, 0);
        acc[nt] = __builtin_amdgcn_mfma_f32_16x16x32_bf16(a3, Bf[3][nt], acc[nt], 0, 0, 0);
      }
      // epilogue: lane holds D[row=q*4+r][col=nt*16+m]
#pragma unroll
      for (int r = 0; r < 4; ++r) {
        int orow = tile * 16 + q * 4 + r;
        float sc = onorm_base[orow];
        float* orow_p = out_b + (size_t)orow * HID;
        bf16_t* erow_p = embs_b + (size_t)orow * HID;
#pragma unroll
        for (int nt = 0; nt < 4; ++nt) {
          int n = nt * 16 + m;
          float v = fmaxf(acc[nt][r] + bs[n], 0.f);
          orow_p[n] = v;
          erow_p[n] = f2bf(v * sc);
        }
      }
    }
    return;
  }

  // ---- f32 fallback (exact fp32 VALU path) ----
  float* Ws = (float*)smem;
  {
    const float* W = (const float*)Wv;
    for (int i = t; i < DIM * HID; i += 256) Ws[i] = W[i];
    if (t < HID) bs[t] = ((const float*)biasv)[t];
  }
  __syncthreads();
  int rl = t >> 4;
  int jq = t & 15;
  for (int rbase = bx * 16; rbase < rows; rbase += EMB_HALF * 16) {
    int row = rbase + rl;
    if (row >= rows) continue;
    float a0 = 0.f, a1 = 0.f, a2 = 0.f, a3 = 0.f;
    const float* fr = (const float*)featv + (size_t)row * DIM;
    for (int k0 = 0; k0 < DIM; k0 += 4) {
      float4 f4 = *(const float4*)(fr + k0);
      float fk[4] = {f4.x, f4.y, f4.z, f4.w};
#pragma unroll
      for (int kk = 0; kk < 4; ++kk) {
        const float* wr = &Ws[(k0 + kk) * HID + jq * 4];
        a0 += fk[kk] * wr[0];
        a1 += fk[kk] * wr[1];
        a2 += fk[kk] * wr[2];
        a3 += fk[kk] * wr[3];
      }
    }
    float4 r;
    r.x = fmaxf(a0 + bs[jq * 4 + 0], 0.f);
    r.y = fmaxf(a1 + bs[jq * 4 + 1], 0.f);
    r.z = fmaxf(a2 + bs[jq * 4 + 2], 0.f);
    r.w = fmaxf(a3 + bs[jq * 4 + 3], 0.f);
    *(float4*)&out_b[(size_t)row * HID + jq * 4] = r;
    float sc = onorm_base[row];
    uint2 p;
    p.x = (unsigned int)f2bf(r.x * sc) | ((unsigned int)f2bf(r.y * sc) << 16);
    p.y = (unsigned int)f2bf(r.z * sc) | ((unsigned int)f2bf(r.w * sc) << 16);
    *(uint2*)&embs_b[(size_t)row * HID + jq * 4] = p;
  }
}

// ---------------- gather layer 1: TWO nodes per wave ----------------
// csr_src entries are element offsets (node*HID) -> addr = embs + off + l8.
__global__ __launch_bounds__(256) void k_gather1(const bf16_t* __restrict__ embs,
                                                 const float* __restrict__ onorm,
                                                 const float* __restrict__ inorm,
                                                 const int* __restrict__ row_ptr,
                                                 const int* __restrict__ csr_src,
                                                 bf16_t* __restrict__ e1s) {
  if (blockIdx.x == 0 && threadIdx.x < 32)
    ((unsigned int*)(e1s + (size_t)NN * HID))[threadIdx.x] = 0u;  // e1s zeros row
  int lane = threadIdx.x & 63;
  int h = lane >> 5;            // node sub-id within wave
  int g = (lane >> 3) & 3;      // 4 edge-groups
  int l8 = (lane & 7) * 8;      // column base (8 bf16 = 16B per lane)
  int n = blockIdx.x * 8 + (threadIdx.x >> 6) * 2 + h;
  int beg = row_ptr[n], end = row_ptr[n + 1];
  f32x2 a[4];
#pragma unroll
  for (int j = 0; j < 4; ++j) a[j] = (f32x2)(0.f);
  for (int base = beg; base < end; base += 16) {
    int sv[4];
#pragma unroll
    for (int k = 0; k < 4; ++k) {
      int ee = base + k * 4 + g;
      int raw = csr_src[ee];             // always in-bounds (32-entry pad)
      sv[k] = (ee < end) ? raw : ZROFF;  // tail -> zeros row
    }
#pragma unroll
    for (int k = 0; k < 4; ++k) {
      uint4 u = *(const uint4*)(embs + sv[k] + l8);
      a[0] += unpack2(u.x);
      a[1] += unpack2(u.y);
      a[2] += unpack2(u.z);
      a[3] += unpack2(u.w);
    }
  }
#pragma unroll
  for (int j = 0; j < 4; ++j) {    // reduce over g (stays within half-wave)
    a[j].x += __shfl_xor(a[j].x, 8);
    a[j].y += __shfl_xor(a[j].y, 8);
    a[j].x += __shfl_xor(a[j].x, 16);
    a[j].y += __shfl_xor(a[j].y, 16);
  }
  if (g == 0) {
    float sc = inorm[n] * onorm[n];   // pre-scale for next gather
    uint4 p;
    p.x = (unsigned int)f2bf(a[0].x * sc) | ((unsigned int)f2bf(a[0].y * sc) << 16);
    p.y = (unsigned int)f2bf(a[1].x * sc) | ((unsigned int)f2bf(a[1].y * sc) << 16);
    p.z = (unsigned int)f2bf(a[2].x * sc) | ((unsigned int)f2bf(a[2].y * sc) << 16);
    p.w = (unsigned int)f2bf(a[3].x * sc) | ((unsigned int)f2bf(a[3].y * sc) << 16);
    *(uint4*)(e1s + (size_t)n * HID + l8) = p;
  }
}

// ---------------- gather layer 2 + combine + side; TWO nodes per wave ----------------
__global__ __launch_bounds__(256) void k_gather2c(float* __restrict__ emb0,
                                                  const bf16_t* __restrict__ e1s,
                                                  const void* __restrict__ sidev,
                                                  const int* __restrict__ flag,
                                                  const float* __restrict__ onorm,
                                                  const float* __restrict__ inorm,
                                                  const int* __restrict__ row_ptr,
                                                  const int* __restrict__ csr_src,
                                                  bf16_t* __restrict__ fin_bf) {
  int lane = threadIdx.x & 63;
  int h = lane >> 5;
  int g = (lane >> 3) & 3;
  int l8 = (lane & 7) * 8;
  int n = blockIdx.x * 8 + (threadIdx.x >> 6) * 2 + h;
  int beg = row_ptr[n], end = row_ptr[n + 1];
  f32x2 a[4];
#pragma unroll
  for (int j = 0; j < 4; ++j) a[j] = (f32x2)(0.f);
  for (int base = beg; base < end; base += 16) {
    int sv[4];
#pragma unroll
    for (int k = 0; k < 4; ++k) {
      int ee = base + k * 4 + g;
      int raw = csr_src[ee];
      sv[k] = (ee < end) ? raw : ZROFF;
    }
#pragma unroll
    for (int k = 0; k < 4; ++k) {
      uint4 u = *(const uint4*)(e1s + sv[k] + l8);
      a[0] += unpack2(u.x);
      a[1] += unpack2(u.y);
      a[2] += unpack2(u.z);
      a[3] += unpack2(u.w);
    }
  }
#pragma unroll
  for (int j = 0; j < 4; ++j) {
    a[j].x += __shfl_xor(a[j].x, 8);
    a[j].y += __shfl_xor(a[j].y, 8);
    a[j].x += __shfl_xor(a[j].x, 16);
    a[j].y += __shfl_xor(a[j].y, 16);
  }
  if (g == 0) {
    float aa[8] = {a[0].x, a[0].y, a[1].x, a[1].y, a[2].x, a[2].y, a[3].x, a[3].y};
    float inorm_n = inorm[n];
    float inv_on = 1.0f / onorm[n];     // e1 = e1s / onorm
    size_t off = (size_t)n * HID + l8;
    uint4 u = *(const uint4*)(e1s + off);
    unsigned int w[4] = {u.x, u.y, u.z, u.w};
    float e1v[8];
#pragma unroll
    for (int j = 0; j < 4; ++j) {
      e1v[2 * j]     = bf2f((unsigned short)(w[j] & 0xffffu)) * inv_on;
      e1v[2 * j + 1] = bf2f((unsigned short)(w[j] >> 16)) * inv_on;
    }
    float4 b0 = *(const float4*)&emb0[off];
    float4 b1 = *(const float4*)&emb0[off + 4];
    float bb[8] = {b0.x, b0.y, b0.z, b0.w, b1.x, b1.y, b1.z, b1.w};
    const float s2 = 1.f / 3.f;
    float vv[8];
#pragma unroll
    for (int j = 0; j < 8; ++j)
      vv[j] = bb[j] + 0.5f * e1v[j] + s2 * aa[j] * inorm_n;
    if (n >= NU) {
      size_t soff = (size_t)(n - NU) * HID + l8;
      if (flag[0] != 0) {
        float4 s0 = *(const float4*)((const float*)sidev + soff);
        float4 s1 = *(const float4*)((const float*)sidev + soff + 4);
        vv[0] += s0.x; vv[1] += s0.y; vv[2] += s0.z; vv[3] += s0.w;
        vv[4] += s1.x; vv[5] += s1.y; vv[6] += s1.z; vv[7] += s1.w;
      } else {
        uint4 su = *(const uint4*)((const bf16_t*)sidev + soff);
        unsigned int sw[4] = {su.x, su.y, su.z, su.w};
#pragma unroll
        for (int j = 0; j < 4; ++j) {
          vv[2 * j]     += bf2f((unsigned short)(sw[j] & 0xffffu));
          vv[2 * j + 1] += bf2f((unsigned short)(sw[j] >> 16));
        }
      }
    }
    float4 o0, o1;
    o0.x = vv[0]; o0.y = vv[1]; o0.z = vv[2]; o0.w = vv[3];
    o1.x = vv[4]; o1.y = vv[5]; o1.z = vv[6]; o1.w = vv[7];
    *(float4*)&emb0[off] = o0;
    *(float4*)&emb0[off + 4] = o1;
    uint4 pb;
    pb.x = (unsigned int)f2bf(vv[0]) | ((unsigned int)f2bf(vv[1]) << 16);
    pb.y = (unsigned int)f2bf(vv[2]) | ((unsigned int)f2bf(vv[3]) << 16);
    pb.z = (unsigned int)f2bf(vv[4]) | ((unsigned int)f2bf(vv[5]) << 16);
    pb.w = (unsigned int)f2bf(vv[6]) | ((unsigned int)f2bf(vv[7]) << 16);
    *(uint4*)(fin_bf + off) = pb;
  }
}

// ---------------- decode via MFMA, pos/neg fused, 2-deep software pipeline ----------------
__global__ __launch_bounds__(256) void k_decode(const bf16_t* __restrict__ zb,  // fin_bf
                                                const void* __restrict__ W1v,
                                                const void* __restrict__ b1v,
                                                const void* __restrict__ W2v,
                                                const void* __restrict__ Tfv,
                                                const void* __restrict__ Tcfv,
                                                const int* __restrict__ flag,
                                                const void* __restrict__ userId,
                                                const void* __restrict__ posId,
                                                const void* __restrict__ negId,
                                                float* __restrict__ out_lf,
                                                float* __restrict__ out_lcf) {
  __shared__ bf16_t W1b[128 * 65];   // padded rows (65) to dodge LDS bank conflicts
  __shared__ float wlast[HID], b1s[HID], W2s[HID];
  const bool f32 = (flag[0] != 0);
  const bool i64 = (flag[1] != 0);
  int t = threadIdx.x;
  if (f32) {
    const float* W1 = (const float*)W1v;
    for (int i = t; i < 128 * 64; i += 256) W1b[(i >> 6) * 65 + (i & 63)] = f2bf(W1[i]);
    if (t < HID) {
      wlast[t] = W1[128 * 64 + t];
      b1s[t] = ((const float*)b1v)[t];
      W2s[t] = ((const float*)W2v)[t];
    }
  } else {
    const bf16_t* W1 = (const bf16_t*)W1v;
    for (int i = t; i < 128 * 64; i += 256) W1b[(i >> 6) * 65 + (i & 63)] = W1[i];
    if (t < HID) {
      wlast[t] = bf2f(W1[128 * 64 + t]);
      b1s[t] = bf2f(((const bf16_t*)b1v)[t]);
      W2s[t] = bf2f(((const bf16_t*)W2v)[t]);
    }
  }
  __syncthreads();
  int wv = t >> 6;
  int lane = t & 63;
  int m = lane & 15;     // A row within tile / B col
  int q = lane >> 4;     // k-subchunk
  short8 Bf[4][4];
#pragma unroll
  for (int c = 0; c < 4; ++c)
#pragma unroll
    for (int nt = 0; nt < 4; ++nt)
#pragma unroll
      for (int j = 0; j < 8; ++j)
        Bf[c][nt][j] = (short)W1b[(c * 32 + q * 8 + j) * 65 + nt * 16 + m];

  const int tiles = NP / 16;  // 12500 pair-tiles
  const int stride = gridDim.x * 4;
  int tile = blockIdx.x * 4 + wv;
  if (tile >= tiles) return;

  // prologue: load first tile's ids + fragments
  int pid = tile * 16 + m;
  int uid = geti(userId, pid, i64);
  int pidx = geti(posId, pid, i64);
  int nidx = geti(negId, pid, i64);
  const bf16_t* ur = zb + (size_t)uid * HID;
  const bf16_t* pr = zb + (size_t)(NU + pidx) * HID;
  const bf16_t* nr = zb + (size_t)(NU + nidx) * HID;
  short8 au0 = *(const short8*)(ur + q * 8);
  short8 au1 = *(const short8*)(ur + 32 + q * 8);
  short8 ap0 = *(const short8*)(pr + q * 8);
  short8 ap1 = *(const short8*)(pr + 32 + q * 8);
  short8 an0 = *(const short8*)(nr + q * 8);
  short8 an1 = *(const short8*)(nr + 32 + q * 8);

  while (true) {
    int ntile = tile + stride;
    bool have_next = (ntile < tiles);
    int uid2 = 0, pidx2 = 0, nidx2 = 0;
    if (have_next) {               // issue next ids early (hide under MFMA)
      int pid2 = ntile * 16 + m;
      uid2 = geti(userId, pid2, i64);
      pidx2 = geti(posId, pid2, i64);
      nidx2 = geti(negId, pid2, i64);
    }
    // T values for current tile
    float tf_p[4], tc_p[4], tf_n[4], tc_n[4];
    int rbase = tile * 16 + q * 4;
    if (f32) {
      float4 t4 = *(const float4*)((const float*)Tfv + rbase);
      float4 c4 = *(const float4*)((const float*)Tcfv + rbase);
      float4 t4n = *(const float4*)((const float*)Tfv + rbase + NP);
      float4 c4n = *(const float4*)((const float*)Tcfv + rbase + NP);
      tf_p[0] = t4.x; tf_p[1] = t4.y; tf_p[2] = t4.z; tf_p[3] = t4.w;
      tc_p[0] = c4.x; tc_p[1] = c4.y; tc_p[2] = c4.z; tc_p[3] = c4.w;
      tf_n[0] = t4n.x; tf_n[1] = t4n.y; tf_n[2] = t4n.z; tf_n[3] = t4n.w;
      tc_n[0] = c4n.x; tc_n[1] = c4n.y; tc_n[2] = c4n.z; tc_n[3] = c4n.w;
    } else {
      const bf16_t* tp = (const bf16_t*)Tfv + rbase;
      const bf16_t* cp = (const bf16_t*)Tcfv + rbase;
#pragma unroll
      for (int r = 0; r < 4; ++r) {
        tf_p[r] = bf2f(tp[r]); tc_p[r] = bf2f(cp[r]);
        tf_n[r] = bf2f(tp[r + NP]); tc_n[r] = bf2f(cp[r + NP]);
      }
    }
    // MFMA + streaming epilogue accumulation (per-nt, same order as before)
    float sfp[4], scp[4], sfn[4], scn[4];
#pragma unroll
    for (int r = 0; r < 4; ++r) { sfp[r] = 0.f; scp[r] = 0.f; sfn[r] = 0.f; scn[r] = 0.f; }
#pragma unroll
    for (int nt = 0; nt < 4; ++nt) {
      f32x4 accu = (f32x4)(0.f);
      accu = __builtin_amdgcn_mfma_f32_16x16x32_bf16(au0, Bf[0][nt], accu, 0, 0, 0);
      accu = __builtin_amdgcn_mfma_f32_16x16x32_bf16(au1, Bf[1][nt], accu, 0, 0, 0);
      f32x4 accp = __builtin_amdgcn_mfma_f32_16x16x32_bf16(ap0, Bf[2][nt], accu, 0, 0, 0);
      accp = __builtin_amdgcn_mfma_f32_16x16x32_bf16(ap1, Bf[3][nt], accp, 0, 0, 0);
      f32x4 accn = __builtin_amdgcn_mfma_f32_16x16x32_bf16(an0, Bf[2][nt], accu, 0, 0, 0);
      accn = __builtin_amdgcn_mfma_f32_16x16x32_bf16(an1, Bf[3][nt], accn, 0, 0, 0);
      int n = nt * 16 + m;
      float b = b1s[n];
      float wl = wlast[n];
      float w2 = W2s[n];
#pragma unroll
      for (int r = 0; r < 4; ++r) {
        float xp = accp[r] + b;
        float xn = accn[r] + b;
        float v0 = xp + tf_p[r] * wl;
        float v1 = xp + tc_p[r] * wl;
        float v2 = xn + tf_n[r] * wl;
        float v3 = xn + tc_n[r] * wl;
        sfp[r] += (v0 > 0.f ? v0 : (__expf(v0) - 1.f)) * w2;
        scp[r] += (v1 > 0.f ? v1 : (__expf(v1) - 1.f)) * w2;
        sfn[r] += (v2 > 0.f ? v2 : (__expf(v2) - 1.f)) * w2;
        scn[r] += (v3 > 0.f ? v3 : (__expf(v3) - 1.f)) * w2;
      }
    }
    // issue next tile's fragment loads now; latency hides under shuffle reduce below
    short8 bu0 = au0, bu1 = au1, bp0 = ap0, bp1 = ap1, bn0 = an0, bn1 = an1;
    if (have_next) {
      const bf16_t* ur2 = zb + (size_t)uid2 * HID;
      const bf16_t* pr2 = zb + (size_t)(NU + pidx2) * HID;
      const bf16_t* nr2 = zb + (size_t)(NU + nidx2) * HID;
      bu0 = *(const short8*)(ur2 + q * 8);
      bu1 = *(const short8*)(ur2 + 32 + q * 8);
      bp0 = *(const short8*)(pr2 + q * 8);
      bp1 = *(const short8*)(pr2 + 32 + q * 8);
      bn0 = *(const short8*)(nr2 + q * 8);
      bn1 = *(const short8*)(nr2 + 32 + q * 8);
    }
#pragma unroll
    for (int r = 0; r < 4; ++r) {
#pragma unroll
      for (int s = 1; s < 16; s <<= 1) {
        sfp[r] += __shfl_xor(sfp[r], s);
        scp[r] += __shfl_xor(scp[r], s);
        sfn[r] += __shfl_xor(sfn[r], s);
        scn[r] += __shfl_xor(scn[r], s);
      }
      if (m == 0) {
        int pr2i = rbase + r;
        out_lf[pr2i] = sfp[r];
        out_lcf[pr2i] = scp[r];
        out_lf[pr2i + NP] = sfn[r];
        out_lcf[pr2i + NP] = scn[r];
      }
    }
    if (!have_next) break;
    tile = ntile;
    au0 = bu0; au1 = bu1; ap0 = bp0; ap1 = bp1; an0 = bn0; an1 = bn1;
  }
}

extern "C" void kernel_launch(void* const* d_in, const int* in_sizes, int n_in,
                              void* d_out, int out_size, void* d_ws, size_t ws_size,
                              hipStream_t stream) {
  (void)in_sizes; (void)n_in; (void)out_size;
  const void* user_f = d_in[0];
  const void* item_f = d_in[1];
  const void* side   = d_in[2];
  const void* Tf     = d_in[3];
  const void* Tcf    = d_in[4];
  const void* Wu     = d_in[5];
  const void* bu     = d_in[6];
  const void* Wi     = d_in[7];
  const void* bi     = d_in[8];
  const void* W1     = d_in[9];
  const void* b1     = d_in[10];
  const void* W2     = d_in[11];
  const void* esrc   = d_in[12];
  const void* edst   = d_in[13];
  const void* userId = d_in[14];
  const void* posId  = d_in[15];
  const void* negId  = d_in[16];

  const size_t WS_NEEDED = 33602688;
  if (ws_size < WS_NEEDED) return;

  char* ws = (char*)d_ws;
  int*   deg_in  = (int*)(ws + 0);             // 400000
  float* onorm   = (float*)(ws + 400000);      // 400000
  float* inorm   = (float*)(ws + 800000);      // 400000
  int*   row_ptr = (int*)(ws + 1200000);       // 400128 (NN+1 ints, padded)
  int*   bsums   = (int*)(ws + 1600128);       // 1024 (196 ints)
  int*   boffs   = (int*)(ws + 1601152);       // 1024
  int*   flag    = (int*)(ws + 1602176);       // 128
  int*   csr_src = (int*)(ws + 1602304);       // 6.4 MB + 128B pad (NE+32 ints)
  // partial histograms overlay embs/e1s (dead before embed/gather writes):
  unsigned int* pout = (unsigned int*)(ws + 8002432);   // 12.8 MB: [HC2][NN/2] u16-packed
  unsigned int* pin  = (unsigned int*)(ws + 20802560);  // 12.8 MB: ditto -> prefixes
  bf16_t* embs   = (bf16_t*)(ws + 8002432);    // (NN+1) rows bf16; later reused as fin_bf
  bf16_t* e1s    = (bf16_t*)(ws + 20802560);   // (NN+1) rows bf16
  bf16_t* fin_bf = embs;                       // embs dead after k_gather1 (stream-ordered)

  float* out     = (float*)d_out;
  float* emb0    = out;
  float* out_lf  = out + (size_t)NN * HID;
  float* out_lcf = out_lf + 2 * NP;

  k_detect<<<1, 64, 0, stream>>>((const bf16_t*)user_f, (const int*)esrc, flag);
  k_hist2<<<2 * HR2 * HC2, 1024, 0, stream>>>(esrc, edst, flag, pout, pin);
  k_reduce<<<196, 256, 0, stream>>>(pout, pin, deg_in, onorm, inorm, bsums);
  k_scan2<<<1, 256, 0, stream>>>(bsums, boffs, 196);
  k_scan3<<<196, 256, 0, stream>>>(deg_in, boffs, row_ptr, csr_src, NN);
  k_fill2<<<HRF * HC2, 1024, 0, stream>>>(esrc, edst, flag, row_ptr, pin, csr_src);
  k_embed2<<<2 * EMB_HALF, 256, 0, stream>>>(user_f, item_f, Wu, bu, Wi, bi, flag,
                                             onorm, emb0, embs);
  k_gather1<<<NN / 8, 256, 0, stream>>>(embs, onorm, inorm, row_ptr, csr_src, e1s);
  k_gather2c<<<NN / 8, 256, 0, stream>>>(emb0, e1s, side, flag, onorm, inorm, row_ptr,
                                         csr_src, fin_bf);
  k_decode<<<1563, 256, 0, stream>>>(fin_bf, W1, b1, W2, Tf, Tcf, flag,
                                     userId, posId, negId, out_lf, out_lcf);
}